// Round 11
// baseline (324.275 us; speedup 1.0000x reference)
//
#include <hip/hip_runtime.h>

#define NN 30000
#define NE 480000
#define BN_EPS 1e-5f
#define EBLK 1875     // NE/256 edge blocks
#define PERMBLK 118   // ceil(NN/256) nperm scatter blocks
#define FBLK 3750     // fused blocks: 8 nodes each (512 thr = 8 waves)
#define PKBLK 469     // ceil(NN*4/256)
#define NSHARD 16     // stats atomic shards

typedef __attribute__((ext_vector_type(8))) short bf16x8;
typedef __attribute__((ext_vector_type(4))) float f32x4;

// ---------------------------------------------------------------------------
// bf16 helpers (RNE pack, cheap unpack)
// ---------------------------------------------------------------------------
__device__ __forceinline__ unsigned short f2bf(float x) {
    unsigned int u = __float_as_uint(x);
    return (unsigned short)((u + 0x7fffu + ((u >> 16) & 1u)) >> 16);
}
__device__ __forceinline__ float bf2f(unsigned short h) {
    return __uint_as_float(((unsigned int)h) << 16);
}

// int64-vs-int32 detect: odd 32-bit words of int64 indices < 2^31 are all 0.
__device__ __forceinline__ int detect64(const unsigned int* __restrict__ ei) {
    unsigned int v = ei[1] | ei[3] | ei[5] | ei[7] |
                     ei[9] | ei[11] | ei[13] | ei[15];
    return v == 0u;
}
__device__ __forceinline__ int load_idx(const void* ei, int is64, int pos) {
    if (is64) return (int)((const long long*)ei)[pos];
    return ((const int*)ei)[pos];
}

// ---------------------------------------------------------------------------
// prep ∥ hist (one dispatch; disjoint outputs; degi pre-zeroed by memset):
//   blocks [0,1875):    x -> xbf (bf16)
//   blocks [1875,2067): pack W0..W2 into MFMA B-fragment order (R5-verified)
//   blocks [2067,2072): zero stats shards + dcur (4160 floats)
//   blocks [2072,3947): dst-degree histogram
// ---------------------------------------------------------------------------
__global__ __launch_bounds__(256) void k_prep_hist(const float* __restrict__ x,
                                                   const float* __restrict__ W0,
                                                   const float* __restrict__ W1,
                                                   const float* __restrict__ W2,
                                                   const void* __restrict__ ei,
                                                   ushort* __restrict__ xbf,
                                                   ushort* __restrict__ wb,
                                                   int4* __restrict__ statz,
                                                   int* __restrict__ degi) {
    int b = blockIdx.x;
    int tid = threadIdx.x;
    if (b < 1875) {
        int t = b * 256 + tid;  // < 480000 = NN*64/4
        float4 v = reinterpret_cast<const float4*>(x)[t];
        ushort4 o;
        o.x = f2bf(v.x); o.y = f2bf(v.y); o.z = f2bf(v.z); o.w = f2bf(v.w);
        reinterpret_cast<ushort4*>(xbf)[t] = o;
    } else if (b < 2067) {
        int t2 = (b - 1875) * 256 + tid;  // < 49152
        int layer = t2 >> 14;
        int r = t2 & 16383;
        int ot = r >> 12;
        int kb = (r >> 9) & 7;
        int l = (r >> 3) & 63;
        int e = r & 7;
        int k = kb * 32 + (l >> 4) * 8 + e;
        int o = ot * 16 + (l & 15);
        int m = k >> 6;
        int kk = k & 63;
        const float* W = (layer == 0) ? W0 : (layer == 1) ? W1 : W2;
        wb[t2] = f2bf(W[(m * 64 + o) * 64 + kk]);
    } else if (b < 2072) {
        int i = (b - 2067) * 256 + tid;
        if (i < 1040) statz[i] = make_int4(0, 0, 0, 0);  // stats(4096f)+dcur(64f)
    } else {
        int e = (b - 2072) * 256 + tid;  // < NE
        int is64 = detect64((const unsigned int*)ei);
        int d = load_idx(ei, is64, NE + e);
        atomicAdd(&degi[d], 1);
    }
}

// ---------------------------------------------------------------------------
// scan: ONE block, 1024 threads. Coalesced load of degi into 120 KB LDS;
// thread-local prefix (30/thread) + block scan -> rowptr. Additionally:
// 64-bin degree histogram (wave-private sub-hists -> bounded LDS-atomic
// serialization) -> exclusive scan -> dbase[64] for the counting sort.
// ---------------------------------------------------------------------------
__global__ __launch_bounds__(1024) void k_scan(const int* __restrict__ degi,
                                               int* __restrict__ rowptr,
                                               int* __restrict__ dbase) {
    __shared__ int buf[30720];   // 120 KB
    __shared__ int sm[1024];
    __shared__ int whist[16][64];
    int t = threadIdx.x;
    for (int i = t; i < 30720; i += 1024)
        buf[i] = (i < NN) ? degi[i] : 0;
    whist[t >> 6][t & 63] = 0;
    __syncthreads();
    const int PER = 30;
    int base = t * PER;
    int wv = t >> 6;
    int loc[PER];
    int sum = 0;
#pragma unroll
    for (int i = 0; i < PER; ++i) {
        int d = buf[base + i];
        loc[i] = sum;
        sum += d;
        if (base + i < NN) {
            int bn = d > 63 ? 63 : d;
            atomicAdd(&whist[wv][bn], 1);
        }
    }
    sm[t] = sum;
    __syncthreads();
    for (int off = 1; off < 1024; off <<= 1) {
        int add = (t >= off) ? sm[t - off] : 0;
        __syncthreads();
        sm[t] += add;
        __syncthreads();
    }
    int tb = sm[t] - sum;
#pragma unroll
    for (int i = 0; i < PER; ++i) {
        int idx = base + i;
        if (idx < NN) rowptr[idx] = tb + loc[i];
    }
    if (t == 0) rowptr[NN] = NE;
    __syncthreads();
    if (t < 64) {
        int s = 0;
#pragma unroll
        for (int w = 0; w < 16; ++w) s += whist[w][t];
        sm[t] = s;
    }
    __syncthreads();
    if (t == 0) {
        int run = 0;
        for (int bn = 0; bn < 64; ++bn) {
            int v = sm[bn];
            dbase[bn] = run;
            run += v;
        }
    }
}

// ---------------------------------------------------------------------------
// p0 (layer 0, no fold): p[n][m] = x[n,:] @ U0[m,:]  (x fp32)
// ---------------------------------------------------------------------------
__device__ __forceinline__ void dev_pk0(const float* __restrict__ h,
                                        const float* __restrict__ U,
                                        float* __restrict__ pout, int vb) {
    __shared__ float usc_s[4][64];
    int t = threadIdx.x;
    {
        int m = t >> 6, k = t & 63;
        usc_s[m][k] = U[m * 64 + k];
    }
    __syncthreads();
    int idx = vb * 256 + t;
    if (idx < NN * 4) {
        int n = idx >> 2, m = idx & 3;
        const float4* hn = reinterpret_cast<const float4*>(h) + (size_t)n * 16;
        const float* um = usc_s[m];
        float a = 0.0f;
#pragma unroll
        for (int j = 0; j < 16; ++j) {
            float4 hv = hn[j];
            a += hv.x * um[4 * j + 0] + hv.y * um[4 * j + 1] +
                 hv.z * um[4 * j + 2] + hv.w * um[4 * j + 3];
        }
        pout[idx] = a;
    }
}

// ---------------------------------------------------------------------------
// Fused dispatch:
//   blocks [0,1875):          CSR scatter (cursor-free atomicSub on degi)
//   blocks [1875,1993):       nperm counting-sort scatter (degree from the
//                             read-only rowptr — degi is being consumed by
//                             the CSR branch concurrently)
//   blocks [1993,1993+469):   p0 = x@U0^T
// ---------------------------------------------------------------------------
__global__ __launch_bounds__(256) void k_scatter_pk0(const void* __restrict__ ei,
                                                     const int* __restrict__ rowptr,
                                                     int* __restrict__ degi,
                                                     int* __restrict__ csr,
                                                     const int* __restrict__ dbase,
                                                     int* __restrict__ dcur,
                                                     int* __restrict__ nperm,
                                                     const float* __restrict__ x,
                                                     const float* __restrict__ U0,
                                                     float* __restrict__ p) {
    if (blockIdx.x < EBLK) {
        int is64 = detect64((const unsigned int*)ei);
        int e = blockIdx.x * 256 + threadIdx.x;
        int s = load_idx(ei, is64, e);
        int d = load_idx(ei, is64, NE + e);
        int old = atomicSub(&degi[d], 1);
        csr[rowptr[d] + old - 1] = s;
    } else if (blockIdx.x < EBLK + PERMBLK) {
        int idx = (blockIdx.x - EBLK) * 256 + threadIdx.x;
        if (idx < NN) {
            int deg = rowptr[idx + 1] - rowptr[idx];
            int bn = deg > 63 ? 63 : deg;
            int pos = dbase[bn] + atomicAdd(&dcur[bn], 1);
            nperm[pos] = idx;
        }
    } else {
        dev_pk0(x, U0, p, blockIdx.x - EBLK - PERMBLK);
    }
}

// ---------------------------------------------------------------------------
// k_pk (fold layers): sums stats shards -> sc/sh; writes scv + cstv (block 0)
// and p[n][m] = hbf[n,:] @ (U[m,:]*sc), reading bf16 features directly.
// ---------------------------------------------------------------------------
__global__ __launch_bounds__(256) void k_pk(const ushort* __restrict__ hbf,
                                            const float* __restrict__ U,
                                            const float* __restrict__ statsS,
                                            const float* __restrict__ g,
                                            const float* __restrict__ W,
                                            const float* __restrict__ bt,
                                            float* __restrict__ pout,
                                            float* __restrict__ cstv_out,
                                            float* __restrict__ scv_out) {
    __shared__ float usc_s[4][64];
    __shared__ float sc_l[64];
    __shared__ float sh_l[64];
    int t = threadIdx.x;
    if (t < 64) {
        float s1 = 0.0f, s2 = 0.0f;
#pragma unroll
        for (int sh = 0; sh < NSHARD; ++sh) {
            s1 += statsS[sh * 128 + t];
            s2 += statsS[sh * 128 + 64 + t];
        }
        const float invN = 1.0f / (float)NN;
        float mu = s1 * invN;
        float var = s2 * invN - mu * mu;
        float sc = rsqrtf(var + BN_EPS) * g[t];
        sc_l[t] = sc;
        sh_l[t] = bt[t] - mu * sc;
        if (blockIdx.x == 0) scv_out[t] = sc;
    }
    __syncthreads();
    {
        int m = t >> 6, k = t & 63;
        usc_s[m][k] = U[m * 64 + k] * sc_l[k];
    }
    __syncthreads();
    int idx = blockIdx.x * 256 + t;
    if (idx < NN * 4) {
        int n = idx >> 2, m = idx & 3;
        const uint4* hn = reinterpret_cast<const uint4*>(hbf + (size_t)n * 64);
        const float* um = usc_s[m];
        float a = 0.0f;
#pragma unroll
        for (int j = 0; j < 8; ++j) {
            uint4 v = hn[j];
            a += bf2f((unsigned short)v.x) * um[8 * j + 0] +
                 bf2f((unsigned short)(v.x >> 16)) * um[8 * j + 1] +
                 bf2f((unsigned short)v.y) * um[8 * j + 2] +
                 bf2f((unsigned short)(v.y >> 16)) * um[8 * j + 3] +
                 bf2f((unsigned short)v.z) * um[8 * j + 4] +
                 bf2f((unsigned short)(v.z >> 16)) * um[8 * j + 5] +
                 bf2f((unsigned short)v.w) * um[8 * j + 6] +
                 bf2f((unsigned short)(v.w >> 16)) * um[8 * j + 7];
        }
        pout[idx] = a;
    }
    if (blockIdx.x == 0) {
        float s = 0.0f;
        const float* wr = W + (size_t)t * 64;
#pragma unroll 8
        for (int k = 0; k < 64; ++k) s += sh_l[k] * wr[k];
        cstv_out[t] = s;
    }
}

// ---------------------------------------------------------------------------
// Fused aggregate + GEMM, 8-wave gang over DEGREE-SORTED nodes.
// n = nperm[bid*8+wid]: each gang's 8 waves have near-identical degree, so
// the barrier straggler (E[max8 Poisson] ≈ 22 vs mean 16, ~33% excess) ≈ 0.
// Phase A: wave per node, gather-aggregate, bf16 z row -> LDS + zs + nid.
// ONE barrier. Phase B: waves 0..3 one 16-col o-tile each over the 8 nodes
// (A rows 8..15 clamped/discarded); waves 4..7 exit.
// ---------------------------------------------------------------------------
template <int FOLD, int STATS>
__global__ __launch_bounds__(512, 4) void k_fused(const int* __restrict__ nperm,
                                                  const int* __restrict__ rowptr,
                                                  const int* __restrict__ csr,
                                                  const float* __restrict__ p,
                                                  const ushort* __restrict__ hbf_in,
                                                  const float* __restrict__ cvec,
                                                  const float* __restrict__ scv,
                                                  const float* __restrict__ cstvg,
                                                  const ushort* __restrict__ wb,
                                                  const float* __restrict__ bvec,
                                                  float* __restrict__ hout,
                                                  ushort* __restrict__ hbfout,
                                                  float* __restrict__ stats_out) {
    __shared__ float4 attn_s[8][64];
    __shared__ int src_s[8][64];
    __shared__ ushort zrow[8][272];   // 544B stride: 16B-aligned rows
    __shared__ float4 zs_s[8];
    __shared__ int nid_s[8];
    __shared__ float cstv_s[256];

    int t = threadIdx.x;
    int wid = t >> 6;
    int lane = t & 63;
    int n = nperm[blockIdx.x * 8 + wid];   // wave-uniform broadcast load
    if (lane == 0) nid_s[wid] = n;
    const float4* p4 = reinterpret_cast<const float4*>(p);

    if (FOLD && t < 256) cstv_s[t] = cstvg[t];

    float scl = FOLD ? scv[lane] : 1.0f;

    float4 cv = make_float4(cvec[0], cvec[1], cvec[2], cvec[3]);
    float smx = fmaxf(fmaxf(cv.x, cv.y), fmaxf(cv.z, cv.w));
    float se0 = __expf(cv.x - smx), se1 = __expf(cv.y - smx);
    float se2 = __expf(cv.z - smx), se3 = __expf(cv.w - smx);
    float sinv = 1.0f / (se0 + se1 + se2 + se3);
    float sl0 = se0 * sinv, sl1 = se1 * sinv, sl2 = se2 * sinv, sl3 = se3 * sinv;

    float4 pd = p4[n];
    float4 pdc = make_float4(pd.x + cv.x, pd.y + cv.y, pd.z + cv.z, pd.w + cv.w);
    float hs = bf2f(hbf_in[(unsigned)(n * 64 + lane)]);
    float acc0 = sl0 * hs, acc1 = sl1 * hs, acc2 = sl2 * hs, acc3 = sl3 * hs;
    float zt0 = sl0, zt1 = sl1, zt2 = sl2, zt3 = sl3;

    int start = rowptr[n];
    int end = rowptr[n + 1];
    for (int j = start; j < end; j += 64) {
        int chunk = end - j;
        if (chunk > 64) chunk = 64;
        if (lane < chunk) {
            int s = csr[j + lane];
            float4 q = p4[(unsigned)s];
            float l0 = pdc.x - q.x;
            float l1 = pdc.y - q.y;
            float l2 = pdc.z - q.z;
            float l3 = pdc.w - q.w;
            float mx = fmaxf(fmaxf(l0, l1), fmaxf(l2, l3));  // REQUIRED (R5 NaN)
            float e0 = __expf(l0 - mx);
            float e1 = __expf(l1 - mx);
            float e2 = __expf(l2 - mx);
            float e3 = __expf(l3 - mx);
            float inv = 1.0f / (e0 + e1 + e2 + e3);
            attn_s[wid][lane] = make_float4(e0 * inv, e1 * inv, e2 * inv, e3 * inv);
            src_s[wid][lane] = s;
        }
        int k = 0;
        for (; k + 4 <= chunk; k += 4) {
            float4 a0 = attn_s[wid][k];
            int s0 = src_s[wid][k];
            float4 a1 = attn_s[wid][k + 1];
            int s1 = src_s[wid][k + 1];
            float4 a2 = attn_s[wid][k + 2];
            int s2 = src_s[wid][k + 2];
            float4 a3 = attn_s[wid][k + 3];
            int s3 = src_s[wid][k + 3];
            float h0 = bf2f(hbf_in[(unsigned)(s0 * 64 + lane)]);
            float h1 = bf2f(hbf_in[(unsigned)(s1 * 64 + lane)]);
            float h2 = bf2f(hbf_in[(unsigned)(s2 * 64 + lane)]);
            float h3 = bf2f(hbf_in[(unsigned)(s3 * 64 + lane)]);
            acc0 += a0.x * h0 + a1.x * h1 + a2.x * h2 + a3.x * h3;
            acc1 += a0.y * h0 + a1.y * h1 + a2.y * h2 + a3.y * h3;
            acc2 += a0.z * h0 + a1.z * h1 + a2.z * h2 + a3.z * h3;
            acc3 += a0.w * h0 + a1.w * h1 + a2.w * h2 + a3.w * h3;
            zt0 += a0.x + a1.x + a2.x + a3.x;
            zt1 += a0.y + a1.y + a2.y + a3.y;
            zt2 += a0.z + a1.z + a2.z + a3.z;
            zt3 += a0.w + a1.w + a2.w + a3.w;
        }
        for (; k < chunk; ++k) {
            float4 a0 = attn_s[wid][k];
            int s0 = src_s[wid][k];
            float h0 = bf2f(hbf_in[(unsigned)(s0 * 64 + lane)]);
            acc0 += a0.x * h0;
            acc1 += a0.y * h0;
            acc2 += a0.z * h0;
            acc3 += a0.w * h0;
            zt0 += a0.x; zt1 += a0.y; zt2 += a0.z; zt3 += a0.w;
        }
    }

    float invD = 1.0f / (float)(end - start + 1);
    float s = invD * scl;
    {
        ushort* zr = &zrow[wid][0];
        zr[lane]       = f2bf(acc0 * s);
        zr[64 + lane]  = f2bf(acc1 * s);
        zr[128 + lane] = f2bf(acc2 * s);
        zr[192 + lane] = f2bf(acc3 * s);
        if (lane == 0)
            zs_s[wid] = make_float4(zt0 * invD, zt1 * invD, zt2 * invD, zt3 * invD);
    }
    __syncthreads();

    // ---- phase B: waves 0..3, one o-tile each; waves 4..7 done ----
    if (wid >= 4) return;

    int col = lane & 15;
    int grp = lane >> 4;
    int r = (col < 8) ? col : 7;        // A rows 8..15 clamped (discarded)
    const ushort* zr = &zrow[r][0];
    const ushort* wbp = wb + ((size_t)(wid * 8) * 64 + lane) * 8;
    f32x4 acc = {0.0f, 0.0f, 0.0f, 0.0f};
#pragma unroll
    for (int kb = 0; kb < 8; ++kb) {
        bf16x8 a = *reinterpret_cast<const bf16x8*>(zr + kb * 32 + grp * 8);
        bf16x8 b = *reinterpret_cast<const bf16x8*>(wbp + (size_t)kb * 512);
        acc = __builtin_amdgcn_mfma_f32_16x16x32_bf16(a, b, acc, 0, 0, 0);
    }

    // D layout: row=(lane>>4)*4+i, col=lane&15. Valid rows 0..7 -> grp<2.
    float ls = 0.0f, lq = 0.0f;
    if (grp < 2) {
        int o = wid * 16 + col;
        float bval = bvec[o];
#pragma unroll
        for (int i = 0; i < 4; ++i) {
            int nn = nid_s[grp * 4 + i];
            float v = acc[i] + bval;
            if (FOLD) {
                float4 zv = zs_s[grp * 4 + i];
                v += zv.x * cstv_s[o] + zv.y * cstv_s[64 + o] +
                     zv.z * cstv_s[128 + o] + zv.w * cstv_s[192 + o];
            }
            if (STATS) {
                v = fmaxf(v, 0.0f);
                hbfout[(size_t)nn * 64 + o] = f2bf(v);
                ls += v;
                lq += v * v;
            } else {
                hout[(size_t)nn * 64 + o] = v;   // final layer: fp32 out
            }
        }
        if (STATS) {
            ls += __shfl_xor(ls, 16, 64);
            lq += __shfl_xor(lq, 16, 64);
            if (lane < 16) {
                float* so = stats_out + (blockIdx.x & (NSHARD - 1)) * 128;
                atomicAdd(&so[o], ls);
                atomicAdd(&so[64 + o], lq);
            }
        }
    }
}

extern "C" void kernel_launch(void* const* d_in, const int* in_sizes, int n_in,
                              void* d_out, int out_size, void* d_ws, size_t ws_size,
                              hipStream_t stream) {
    const float* x = (const float*)d_in[0];
    const void* ei = d_in[1];
    const float* W0 = (const float*)d_in[2];
    const float* U0 = (const float*)d_in[3];
    const float* c0 = (const float*)d_in[4];
    const float* b0 = (const float*)d_in[5];
    const float* g0 = (const float*)d_in[6];
    const float* bt0 = (const float*)d_in[7];
    const float* W1 = (const float*)d_in[8];
    const float* U1 = (const float*)d_in[9];
    const float* c1 = (const float*)d_in[10];
    const float* b1 = (const float*)d_in[11];
    const float* g1 = (const float*)d_in[12];
    const float* bt1 = (const float*)d_in[13];
    const float* W2 = (const float*)d_in[14];
    const float* U2 = (const float*)d_in[15];
    const float* c2 = (const float*)d_in[16];
    const float* b2 = (const float*)d_in[17];

    // workspace layout — all 16B-aligned
    ushort* xbf = (ushort*)d_ws;                      // NN*64 bf16
    ushort* hbfA = xbf + (size_t)NN * 64;             // NN*64 (double buffer A)
    ushort* hbfB = hbfA + (size_t)NN * 64;            // NN*64 (double buffer B)
    float* p = (float*)(hbfB + (size_t)NN * 64);      // NN*4
    float* cstv = p + (size_t)NN * 4;                 // 256
    float* scv = cstv + 256;                          // 64
    int* degi = (int*)(scv + 64);                     // NN (memset-zeroed)
    float* statsA = (float*)(degi + NN);              // 4096 } zeroed together
    int* dcur = (int*)(statsA + 4096);                // 64   } (1040 int4)
    int* dbase = dcur + 64;                           // 64 (written by scan)
    int* rowptr = dbase + 64;                         // NN+4
    int* csr = rowptr + NN + 4;                       // NE
    ushort* wb = (ushort*)(csr + NE);                 // 3*16384 bf16
    int* nperm = (int*)(wb + 3 * 16384);              // NN
    float* stats0 = statsA;
    float* stats1 = statsA + 2048;

    // 9 stream ops (memset + 8 kernels)
    hipMemsetAsync(degi, 0, sizeof(int) * NN, stream);
    k_prep_hist<<<3947, 256, 0, stream>>>(x, W0, W1, W2, ei, xbf, wb,
                                          (int4*)statsA, degi);
    k_scan<<<1, 1024, 0, stream>>>(degi, rowptr, dbase);
    k_scatter_pk0<<<EBLK + PERMBLK + PKBLK, 256, 0, stream>>>(
        ei, rowptr, degi, csr, dbase, dcur, nperm, x, U0, p);

    // ---- layer 0: read xbf, write hbfA + stats0 shards ----
    k_fused<0, 1><<<FBLK, 512, 0, stream>>>(nperm, rowptr, csr, p, xbf, c0,
                                            nullptr, nullptr, wb, b0,
                                            nullptr, hbfA, stats0);
    // ---- layer 1: fold BN0; read hbfA, write hbfB + stats1 shards ----
    k_pk<<<PKBLK, 256, 0, stream>>>(hbfA, U1, stats0, g0, W1, bt0, p, cstv, scv);
    k_fused<1, 1><<<FBLK, 512, 0, stream>>>(nperm, rowptr, csr, p, hbfA, c1,
                                            scv, cstv, wb + 16384, b1,
                                            nullptr, hbfB, stats1);
    // ---- layer 2: fold BN1; read hbfB, write d_out (fp32) ----
    k_pk<<<PKBLK, 256, 0, stream>>>(hbfB, U2, stats1, g1, W2, bt1, p, cstv, scv);
    k_fused<1, 0><<<FBLK, 512, 0, stream>>>(nperm, rowptr, csr, p, hbfB, c2,
                                            scv, cstv, wb + 32768, b2,
                                            (float*)d_out, nullptr, nullptr);
}

// Round 12
// 299.553 us; speedup vs baseline: 1.0825x; 1.0825x over previous
//
#include <hip/hip_runtime.h>

#define NN 30000
#define NE 480000
#define BN_EPS 1e-5f
#define EBLK 1875     // NE/256 edge blocks
#define FBLK 3750     // fused blocks: 8 nodes each (512 thr = 8 waves)
#define PKBLK 469     // ceil(NN*4/256)
#define NSHARD 16     // stats atomic shards

typedef __attribute__((ext_vector_type(8))) short bf16x8;
typedef __attribute__((ext_vector_type(4))) float f32x4;

// ---------------------------------------------------------------------------
// bf16 helpers (RNE pack, cheap unpack)
// ---------------------------------------------------------------------------
__device__ __forceinline__ unsigned short f2bf(float x) {
    unsigned int u = __float_as_uint(x);
    return (unsigned short)((u + 0x7fffu + ((u >> 16) & 1u)) >> 16);
}
__device__ __forceinline__ float bf2f(unsigned short h) {
    return __uint_as_float(((unsigned int)h) << 16);
}

// int64-vs-int32 detect: odd 32-bit words of int64 indices < 2^31 are all 0.
__device__ __forceinline__ int detect64(const unsigned int* __restrict__ ei) {
    unsigned int v = ei[1] | ei[3] | ei[5] | ei[7] |
                     ei[9] | ei[11] | ei[13] | ei[15];
    return v == 0u;
}
__device__ __forceinline__ int load_idx(const void* ei, int is64, int pos) {
    if (is64) return (int)((const long long*)ei)[pos];
    return ((const int*)ei)[pos];
}

// ---------------------------------------------------------------------------
// prep ∥ hist (one dispatch; disjoint outputs; degi pre-zeroed by memset):
//   blocks [0,1875):    x -> xbf (bf16)
//   blocks [1875,2067): pack W0..W2 into MFMA B-fragment order (R5-verified)
//   blocks [2067,2071): zero stats shards (4096 floats)
//   blocks [2071,3946): dst-degree histogram
// ---------------------------------------------------------------------------
__global__ __launch_bounds__(256) void k_prep_hist(const float* __restrict__ x,
                                                   const float* __restrict__ W0,
                                                   const float* __restrict__ W1,
                                                   const float* __restrict__ W2,
                                                   const void* __restrict__ ei,
                                                   ushort* __restrict__ xbf,
                                                   ushort* __restrict__ wb,
                                                   int4* __restrict__ statz,
                                                   int* __restrict__ degi) {
    int b = blockIdx.x;
    int tid = threadIdx.x;
    if (b < 1875) {
        int t = b * 256 + tid;  // < 480000 = NN*64/4
        float4 v = reinterpret_cast<const float4*>(x)[t];
        ushort4 o;
        o.x = f2bf(v.x); o.y = f2bf(v.y); o.z = f2bf(v.z); o.w = f2bf(v.w);
        reinterpret_cast<ushort4*>(xbf)[t] = o;
    } else if (b < 2067) {
        int t2 = (b - 1875) * 256 + tid;  // < 49152
        int layer = t2 >> 14;
        int r = t2 & 16383;
        int ot = r >> 12;
        int kb = (r >> 9) & 7;
        int l = (r >> 3) & 63;
        int e = r & 7;
        int k = kb * 32 + (l >> 4) * 8 + e;
        int o = ot * 16 + (l & 15);
        int m = k >> 6;
        int kk = k & 63;
        const float* W = (layer == 0) ? W0 : (layer == 1) ? W1 : W2;
        wb[t2] = f2bf(W[(m * 64 + o) * 64 + kk]);
    } else if (b < 2071) {
        statz[(b - 2067) * 256 + tid] = make_int4(0, 0, 0, 0);  // 1024 int4
    } else {
        int e = (b - 2071) * 256 + tid;  // < NE
        int is64 = detect64((const unsigned int*)ei);
        int d = load_idx(ei, is64, NE + e);
        atomicAdd(&degi[d], 1);
    }
}

// ---------------------------------------------------------------------------
// scan: ONE block, 1024 threads. Coalesced load of degi into 120 KB LDS;
// thread-local exclusive prefix (30/thread) + block scan -> rowptr.
// ---------------------------------------------------------------------------
__global__ __launch_bounds__(1024) void k_scan(const int* __restrict__ degi,
                                               int* __restrict__ rowptr) {
    __shared__ int buf[30720];   // 120 KB
    __shared__ int sm[1024];
    int t = threadIdx.x;
    for (int i = t; i < 30720; i += 1024)
        buf[i] = (i < NN) ? degi[i] : 0;
    __syncthreads();
    const int PER = 30;
    int base = t * PER;
    int loc[PER];
    int sum = 0;
#pragma unroll
    for (int i = 0; i < PER; ++i) {
        loc[i] = sum;
        sum += buf[base + i];
    }
    sm[t] = sum;
    __syncthreads();
    for (int off = 1; off < 1024; off <<= 1) {
        int add = (t >= off) ? sm[t - off] : 0;
        __syncthreads();
        sm[t] += add;
        __syncthreads();
    }
    int tb = sm[t] - sum;
#pragma unroll
    for (int i = 0; i < PER; ++i) {
        int idx = base + i;
        if (idx < NN) rowptr[idx] = tb + loc[i];
    }
    if (t == 0) rowptr[NN] = NE;
}

// ---------------------------------------------------------------------------
// p0 (layer 0, no fold): p[n][m] = x[n,:] @ U0[m,:]  (x fp32)
// ---------------------------------------------------------------------------
__device__ __forceinline__ void dev_pk0(const float* __restrict__ h,
                                        const float* __restrict__ U,
                                        float* __restrict__ pout, int vb) {
    __shared__ float usc_s[4][64];
    int t = threadIdx.x;
    {
        int m = t >> 6, k = t & 63;
        usc_s[m][k] = U[m * 64 + k];
    }
    __syncthreads();
    int idx = vb * 256 + t;
    if (idx < NN * 4) {
        int n = idx >> 2, m = idx & 3;
        const float4* hn = reinterpret_cast<const float4*>(h) + (size_t)n * 16;
        const float* um = usc_s[m];
        float a = 0.0f;
#pragma unroll
        for (int j = 0; j < 16; ++j) {
            float4 hv = hn[j];
            a += hv.x * um[4 * j + 0] + hv.y * um[4 * j + 1] +
                 hv.z * um[4 * j + 2] + hv.w * um[4 * j + 3];
        }
        pout[idx] = a;
    }
}

// ---------------------------------------------------------------------------
// Fused: blocks 0..1874 scatter CSR (cursor-free atomicSub on degi, dead
// after scan); blocks 1875.. compute p0 = x@U0^T.
// ---------------------------------------------------------------------------
__global__ __launch_bounds__(256) void k_scatter_pk0(const void* __restrict__ ei,
                                                     const int* __restrict__ rowptr,
                                                     int* __restrict__ degi,
                                                     int* __restrict__ csr,
                                                     const float* __restrict__ x,
                                                     const float* __restrict__ U0,
                                                     float* __restrict__ p) {
    if (blockIdx.x < EBLK) {
        int is64 = detect64((const unsigned int*)ei);
        int e = blockIdx.x * 256 + threadIdx.x;
        int s = load_idx(ei, is64, e);
        int d = load_idx(ei, is64, NE + e);
        int old = atomicSub(&degi[d], 1);
        csr[rowptr[d] + old - 1] = s;
    } else {
        dev_pk0(x, U0, p, blockIdx.x - EBLK);
    }
}

// ---------------------------------------------------------------------------
// k_pk (fold layers): sums stats shards -> sc/sh; writes scv + cstv (block 0)
// and p[n][m] = hbf[n,:] @ (U[m,:]*sc), reading bf16 features directly.
// ---------------------------------------------------------------------------
__global__ __launch_bounds__(256) void k_pk(const ushort* __restrict__ hbf,
                                            const float* __restrict__ U,
                                            const float* __restrict__ statsS,
                                            const float* __restrict__ g,
                                            const float* __restrict__ W,
                                            const float* __restrict__ bt,
                                            float* __restrict__ pout,
                                            float* __restrict__ cstv_out,
                                            float* __restrict__ scv_out) {
    __shared__ float usc_s[4][64];
    __shared__ float sc_l[64];
    __shared__ float sh_l[64];
    int t = threadIdx.x;
    if (t < 64) {
        float s1 = 0.0f, s2 = 0.0f;
#pragma unroll
        for (int sh = 0; sh < NSHARD; ++sh) {
            s1 += statsS[sh * 128 + t];
            s2 += statsS[sh * 128 + 64 + t];
        }
        const float invN = 1.0f / (float)NN;
        float mu = s1 * invN;
        float var = s2 * invN - mu * mu;
        float sc = rsqrtf(var + BN_EPS) * g[t];
        sc_l[t] = sc;
        sh_l[t] = bt[t] - mu * sc;
        if (blockIdx.x == 0) scv_out[t] = sc;
    }
    __syncthreads();
    {
        int m = t >> 6, k = t & 63;
        usc_s[m][k] = U[m * 64 + k] * sc_l[k];
    }
    __syncthreads();
    int idx = blockIdx.x * 256 + t;
    if (idx < NN * 4) {
        int n = idx >> 2, m = idx & 3;
        const uint4* hn = reinterpret_cast<const uint4*>(hbf + (size_t)n * 64);
        const float* um = usc_s[m];
        float a = 0.0f;
#pragma unroll
        for (int j = 0; j < 8; ++j) {
            uint4 v = hn[j];
            a += bf2f((unsigned short)v.x) * um[8 * j + 0] +
                 bf2f((unsigned short)(v.x >> 16)) * um[8 * j + 1] +
                 bf2f((unsigned short)v.y) * um[8 * j + 2] +
                 bf2f((unsigned short)(v.y >> 16)) * um[8 * j + 3] +
                 bf2f((unsigned short)v.z) * um[8 * j + 4] +
                 bf2f((unsigned short)(v.z >> 16)) * um[8 * j + 5] +
                 bf2f((unsigned short)v.w) * um[8 * j + 6] +
                 bf2f((unsigned short)(v.w >> 16)) * um[8 * j + 7];
        }
        pout[idx] = a;
    }
    if (blockIdx.x == 0) {
        float s = 0.0f;
        const float* wr = W + (size_t)t * 64;
#pragma unroll 8
        for (int k = 0; k < 64; ++k) s += sh_l[k] * wr[k];
        cstv_out[t] = s;
    }
}

// ---------------------------------------------------------------------------
// Fused aggregate + GEMM, 8-wave gang (R9-verified shell). NEW phase A
// gather: lane-group g = lane>>4 handles edge k+g; each lane loads uint2 =
// 4 bf16 channels (cq = (lane&15)*4) of its group's src node -> ONE VMEM
// instruction covers 4 edges (64 gathers/node -> 16). Lane accumulates
// ac[4 heads][4 ch] for its group's edges; butterfly xor16/32 sums the 4
// groups. Staging pads to a multiple of 8 with attn=0/src=n (no guards).
// Self-loop folds into group 0's init. zrow/zs/phase-B byte-identical
// to the verified R9/R10 layout.
// ---------------------------------------------------------------------------
template <int FOLD, int STATS>
__global__ __launch_bounds__(512, 4) void k_fused(const int* __restrict__ rowptr,
                                                  const int* __restrict__ csr,
                                                  const float* __restrict__ p,
                                                  const ushort* __restrict__ hbf_in,
                                                  const float* __restrict__ cvec,
                                                  const float* __restrict__ scv,
                                                  const float* __restrict__ cstvg,
                                                  const ushort* __restrict__ wb,
                                                  const float* __restrict__ bvec,
                                                  float* __restrict__ hout,
                                                  ushort* __restrict__ hbfout,
                                                  float* __restrict__ stats_out) {
    __shared__ float4 attn_s[8][64];
    __shared__ int src_s[8][64];
    __shared__ ushort zrow[8][272];   // 544B stride: 16B-aligned rows
    __shared__ float4 zs_s[8];
    __shared__ float cstv_s[256];

    int t = threadIdx.x;
    int wid = t >> 6;
    int lane = t & 63;
    int n = blockIdx.x * 8 + wid;
    const float4* p4 = reinterpret_cast<const float4*>(p);

    if (FOLD && t < 256) cstv_s[t] = cstvg[t];

    float4 cv = make_float4(cvec[0], cvec[1], cvec[2], cvec[3]);
    float smx = fmaxf(fmaxf(cv.x, cv.y), fmaxf(cv.z, cv.w));
    float se0 = __expf(cv.x - smx), se1 = __expf(cv.y - smx);
    float se2 = __expf(cv.z - smx), se3 = __expf(cv.w - smx);
    float sinv = 1.0f / (se0 + se1 + se2 + se3);
    float sl0 = se0 * sinv, sl1 = se1 * sinv, sl2 = se2 * sinv, sl3 = se3 * sinv;

    float4 pd = p4[n];
    float4 pdc = make_float4(pd.x + cv.x, pd.y + cv.y, pd.z + cv.z, pd.w + cv.w);

    int g = lane >> 4;        // edge subgroup 0..3
    int cq = (lane & 15) * 4; // channel quad base

    float ac[4][4];           // [head][ch-in-quad]
    float zt[4];
    if (g == 0) {             // self-loop: counted once (group 0 only)
        uint2 hv = *reinterpret_cast<const uint2*>(hbf_in + (size_t)n * 64 + cq);
        float h0 = bf2f((unsigned short)hv.x);
        float h1 = bf2f((unsigned short)(hv.x >> 16));
        float h2 = bf2f((unsigned short)hv.y);
        float h3 = bf2f((unsigned short)(hv.y >> 16));
        ac[0][0] = sl0 * h0; ac[0][1] = sl0 * h1; ac[0][2] = sl0 * h2; ac[0][3] = sl0 * h3;
        ac[1][0] = sl1 * h0; ac[1][1] = sl1 * h1; ac[1][2] = sl1 * h2; ac[1][3] = sl1 * h3;
        ac[2][0] = sl2 * h0; ac[2][1] = sl2 * h1; ac[2][2] = sl2 * h2; ac[2][3] = sl2 * h3;
        ac[3][0] = sl3 * h0; ac[3][1] = sl3 * h1; ac[3][2] = sl3 * h2; ac[3][3] = sl3 * h3;
        zt[0] = sl0; zt[1] = sl1; zt[2] = sl2; zt[3] = sl3;
    } else {
#pragma unroll
        for (int m = 0; m < 4; ++m) {
#pragma unroll
            for (int c = 0; c < 4; ++c) ac[m][c] = 0.0f;
            zt[m] = 0.0f;
        }
    }

    int start = rowptr[n];
    int end = rowptr[n + 1];
    for (int j = start; j < end; j += 64) {
        int chunk = end - j;
        if (chunk > 64) chunk = 64;
        int cp = (chunk + 7) & ~7;   // pad to mult of 8 (<= 64)
        if (lane < chunk) {
            int s = csr[j + lane];
            float4 q = p4[(unsigned)s];
            float l0 = pdc.x - q.x;
            float l1 = pdc.y - q.y;
            float l2 = pdc.z - q.z;
            float l3 = pdc.w - q.w;
            float mx = fmaxf(fmaxf(l0, l1), fmaxf(l2, l3));  // REQUIRED (R5 NaN)
            float e0 = __expf(l0 - mx);
            float e1 = __expf(l1 - mx);
            float e2 = __expf(l2 - mx);
            float e3 = __expf(l3 - mx);
            float inv = 1.0f / (e0 + e1 + e2 + e3);
            attn_s[wid][lane] = make_float4(e0 * inv, e1 * inv, e2 * inv, e3 * inv);
            src_s[wid][lane] = s;
        } else if (lane < cp) {       // zero-pad: no guards in gather loop
            attn_s[wid][lane] = make_float4(0.0f, 0.0f, 0.0f, 0.0f);
            src_s[wid][lane] = n;
        }
        for (int k = 0; k < cp; k += 8) {
            int e0i = k + g;
            int e1i = k + 4 + g;
            float4 a0 = attn_s[wid][e0i];
            int s0 = src_s[wid][e0i];
            float4 a1 = attn_s[wid][e1i];
            int s1 = src_s[wid][e1i];
            uint2 v0 = *reinterpret_cast<const uint2*>(hbf_in + (size_t)s0 * 64 + cq);
            uint2 v1 = *reinterpret_cast<const uint2*>(hbf_in + (size_t)s1 * 64 + cq);
            float h00 = bf2f((unsigned short)v0.x);
            float h01 = bf2f((unsigned short)(v0.x >> 16));
            float h02 = bf2f((unsigned short)v0.y);
            float h03 = bf2f((unsigned short)(v0.y >> 16));
            float h10 = bf2f((unsigned short)v1.x);
            float h11 = bf2f((unsigned short)(v1.x >> 16));
            float h12 = bf2f((unsigned short)v1.y);
            float h13 = bf2f((unsigned short)(v1.y >> 16));
            ac[0][0] += a0.x * h00 + a1.x * h10;
            ac[0][1] += a0.x * h01 + a1.x * h11;
            ac[0][2] += a0.x * h02 + a1.x * h12;
            ac[0][3] += a0.x * h03 + a1.x * h13;
            ac[1][0] += a0.y * h00 + a1.y * h10;
            ac[1][1] += a0.y * h01 + a1.y * h11;
            ac[1][2] += a0.y * h02 + a1.y * h12;
            ac[1][3] += a0.y * h03 + a1.y * h13;
            ac[2][0] += a0.z * h00 + a1.z * h10;
            ac[2][1] += a0.z * h01 + a1.z * h11;
            ac[2][2] += a0.z * h02 + a1.z * h12;
            ac[2][3] += a0.z * h03 + a1.z * h13;
            ac[3][0] += a0.w * h00 + a1.w * h10;
            ac[3][1] += a0.w * h01 + a1.w * h11;
            ac[3][2] += a0.w * h02 + a1.w * h12;
            ac[3][3] += a0.w * h03 + a1.w * h13;
            zt[0] += a0.x + a1.x;
            zt[1] += a0.y + a1.y;
            zt[2] += a0.z + a1.z;
            zt[3] += a0.w + a1.w;
        }
    }

    // butterfly: sum the 4 edge-groups (within-group lanes hold identical zt;
    // xor16/32 cross only the group bits -> correct for both ac and zt)
#pragma unroll
    for (int m = 0; m < 4; ++m) {
#pragma unroll
        for (int c = 0; c < 4; ++c) {
            float v = ac[m][c];
            v += __shfl_xor(v, 16, 64);
            v += __shfl_xor(v, 32, 64);
            ac[m][c] = v;
        }
        float z = zt[m];
        z += __shfl_xor(z, 16, 64);
        z += __shfl_xor(z, 32, 64);
        zt[m] = z;
    }

    float invD = 1.0f / (float)(end - start + 1);
    if (g == 0) {   // lanes 0..15 write the full z row (all groups identical)
        float4 sc4 = FOLD ? reinterpret_cast<const float4*>(scv)[lane & 15]
                          : make_float4(1.0f, 1.0f, 1.0f, 1.0f);
        ushort* zr = &zrow[wid][0];
#pragma unroll
        for (int m = 0; m < 4; ++m) {
            ushort4 o;
            o.x = f2bf(ac[m][0] * invD * sc4.x);
            o.y = f2bf(ac[m][1] * invD * sc4.y);
            o.z = f2bf(ac[m][2] * invD * sc4.z);
            o.w = f2bf(ac[m][3] * invD * sc4.w);
            *reinterpret_cast<ushort4*>(zr + m * 64 + cq) = o;
        }
        if (lane == 0)
            zs_s[wid] = make_float4(zt[0] * invD, zt[1] * invD,
                                    zt[2] * invD, zt[3] * invD);
    }
    __syncthreads();

    // ---- phase B: waves 0..3, one o-tile each; waves 4..7 done ----
    if (wid >= 4) return;

    int col = lane & 15;
    int grp = lane >> 4;
    int r = (col < 8) ? col : 7;        // A rows 8..15 clamped (discarded)
    const ushort* zr = &zrow[r][0];
    const ushort* wbp = wb + ((size_t)(wid * 8) * 64 + lane) * 8;
    f32x4 acc = {0.0f, 0.0f, 0.0f, 0.0f};
#pragma unroll
    for (int kb = 0; kb < 8; ++kb) {
        bf16x8 a = *reinterpret_cast<const bf16x8*>(zr + kb * 32 + grp * 8);
        bf16x8 b = *reinterpret_cast<const bf16x8*>(wbp + (size_t)kb * 512);
        acc = __builtin_amdgcn_mfma_f32_16x16x32_bf16(a, b, acc, 0, 0, 0);
    }

    // D layout: row=(lane>>4)*4+i, col=lane&15. Valid rows 0..7 -> grp<2.
    float ls = 0.0f, lq = 0.0f;
    if (grp < 2) {
        int n0 = blockIdx.x * 8;
        int o = wid * 16 + col;
        float bval = bvec[o];
#pragma unroll
        for (int i = 0; i < 4; ++i) {
            int nn = n0 + grp * 4 + i;
            float v = acc[i] + bval;
            if (FOLD) {
                float4 zv = zs_s[grp * 4 + i];
                v += zv.x * cstv_s[o] + zv.y * cstv_s[64 + o] +
                     zv.z * cstv_s[128 + o] + zv.w * cstv_s[192 + o];
            }
            if (STATS) {
                v = fmaxf(v, 0.0f);
                hbfout[(size_t)nn * 64 + o] = f2bf(v);
                ls += v;
                lq += v * v;
            } else {
                hout[(size_t)nn * 64 + o] = v;   // final layer: fp32 out
            }
        }
        if (STATS) {
            ls += __shfl_xor(ls, 16, 64);
            lq += __shfl_xor(lq, 16, 64);
            if (lane < 16) {
                float* so = stats_out + (blockIdx.x & (NSHARD - 1)) * 128;
                atomicAdd(&so[o], ls);
                atomicAdd(&so[64 + o], lq);
            }
        }
    }
}

extern "C" void kernel_launch(void* const* d_in, const int* in_sizes, int n_in,
                              void* d_out, int out_size, void* d_ws, size_t ws_size,
                              hipStream_t stream) {
    const float* x = (const float*)d_in[0];
    const void* ei = d_in[1];
    const float* W0 = (const float*)d_in[2];
    const float* U0 = (const float*)d_in[3];
    const float* c0 = (const float*)d_in[4];
    const float* b0 = (const float*)d_in[5];
    const float* g0 = (const float*)d_in[6];
    const float* bt0 = (const float*)d_in[7];
    const float* W1 = (const float*)d_in[8];
    const float* U1 = (const float*)d_in[9];
    const float* c1 = (const float*)d_in[10];
    const float* b1 = (const float*)d_in[11];
    const float* g1 = (const float*)d_in[12];
    const float* bt1 = (const float*)d_in[13];
    const float* W2 = (const float*)d_in[14];
    const float* U2 = (const float*)d_in[15];
    const float* c2 = (const float*)d_in[16];
    const float* b2 = (const float*)d_in[17];

    // workspace layout — all 16B-aligned
    ushort* xbf = (ushort*)d_ws;                      // NN*64 bf16
    ushort* hbfA = xbf + (size_t)NN * 64;             // NN*64 (double buffer A)
    ushort* hbfB = hbfA + (size_t)NN * 64;            // NN*64 (double buffer B)
    float* p = (float*)(hbfB + (size_t)NN * 64);      // NN*4
    float* cstv = p + (size_t)NN * 4;                 // 256
    float* scv = cstv + 256;                          // 64
    int* degi = (int*)(scv + 64);                     // NN (memset-zeroed)
    float* statsA = (float*)(degi + NN);              // 2*16*128 = 4096
    int* rowptr = (int*)(statsA + 4096);              // NN+4
    int* csr = rowptr + NN + 4;                       // NE
    ushort* wb = (ushort*)(csr + NE);                 // 3*16384 bf16
    float* stats0 = statsA;
    float* stats1 = statsA + 2048;

    // 9 stream ops (memset + 8 kernels)
    hipMemsetAsync(degi, 0, sizeof(int) * NN, stream);
    k_prep_hist<<<3946, 256, 0, stream>>>(x, W0, W1, W2, ei, xbf, wb,
                                          (int4*)statsA, degi);
    k_scan<<<1, 1024, 0, stream>>>(degi, rowptr);
    k_scatter_pk0<<<EBLK + PKBLK, 256, 0, stream>>>(ei, rowptr, degi, csr,
                                                    x, U0, p);

    // ---- layer 0: read xbf, write hbfA + stats0 shards ----
    k_fused<0, 1><<<FBLK, 512, 0, stream>>>(rowptr, csr, p, xbf, c0,
                                            nullptr, nullptr, wb, b0,
                                            nullptr, hbfA, stats0);
    // ---- layer 1: fold BN0; read hbfA, write hbfB + stats1 shards ----
    k_pk<<<PKBLK, 256, 0, stream>>>(hbfA, U1, stats0, g0, W1, bt0, p, cstv, scv);
    k_fused<1, 1><<<FBLK, 512, 0, stream>>>(rowptr, csr, p, hbfA, c1,
                                            scv, cstv, wb + 16384, b1,
                                            nullptr, hbfB, stats1);
    // ---- layer 2: fold BN1; read hbfB, write d_out (fp32) ----
    k_pk<<<PKBLK, 256, 0, stream>>>(hbfB, U2, stats1, g1, W2, bt1, p, cstv, scv);
    k_fused<1, 0><<<FBLK, 512, 0, stream>>>(rowptr, csr, p, hbfB, c2,
                                            scv, cstv, wb + 32768, b2,
                                            (float*)d_out, nullptr, nullptr);
}

// Round 13
// 281.927 us; speedup vs baseline: 1.1502x; 1.0625x over previous
//
#include <hip/hip_runtime.h>

#define NN 30000
#define NE 480000
#define BN_EPS 1e-5f
#define EBLK 1875     // NE/256 edge blocks
#define FBLK 3750     // fused blocks: 8 nodes each (512 thr = 8 waves)
#define PKBLK 469     // ceil(NN*4/256)
#define NSHARD 16     // stats atomic shards

typedef __attribute__((ext_vector_type(8))) short bf16x8;
typedef __attribute__((ext_vector_type(4))) float f32x4;

// ---------------------------------------------------------------------------
// bf16 helpers (RNE pack, cheap unpack)
// ---------------------------------------------------------------------------
__device__ __forceinline__ unsigned short f2bf(float x) {
    unsigned int u = __float_as_uint(x);
    return (unsigned short)((u + 0x7fffu + ((u >> 16) & 1u)) >> 16);
}
__device__ __forceinline__ float bf2f(unsigned short h) {
    return __uint_as_float(((unsigned int)h) << 16);
}

// int64-vs-int32 detect: odd 32-bit words of int64 indices < 2^31 are all 0.
__device__ __forceinline__ int detect64(const unsigned int* __restrict__ ei) {
    unsigned int v = ei[1] | ei[3] | ei[5] | ei[7] |
                     ei[9] | ei[11] | ei[13] | ei[15];
    return v == 0u;
}
__device__ __forceinline__ int load_idx(const void* ei, int is64, int pos) {
    if (is64) return (int)((const long long*)ei)[pos];
    return ((const int*)ei)[pos];
}

// ---------------------------------------------------------------------------
// prep ∥ hist (one dispatch; disjoint outputs; degi pre-zeroed by memset):
//   blocks [0,1875):    x -> xbf (bf16)
//   blocks [1875,2067): pack W0..W2 into MFMA B-fragment order (R5-verified)
//   blocks [2067,2071): zero stats shards (4096 floats)
//   blocks [2071,3946): dst-degree histogram
// ---------------------------------------------------------------------------
__global__ __launch_bounds__(256) void k_prep_hist(const float* __restrict__ x,
                                                   const float* __restrict__ W0,
                                                   const float* __restrict__ W1,
                                                   const float* __restrict__ W2,
                                                   const void* __restrict__ ei,
                                                   ushort* __restrict__ xbf,
                                                   ushort* __restrict__ wb,
                                                   int4* __restrict__ statz,
                                                   int* __restrict__ degi) {
    int b = blockIdx.x;
    int tid = threadIdx.x;
    if (b < 1875) {
        int t = b * 256 + tid;  // < 480000 = NN*64/4
        float4 v = reinterpret_cast<const float4*>(x)[t];
        ushort4 o;
        o.x = f2bf(v.x); o.y = f2bf(v.y); o.z = f2bf(v.z); o.w = f2bf(v.w);
        reinterpret_cast<ushort4*>(xbf)[t] = o;
    } else if (b < 2067) {
        int t2 = (b - 1875) * 256 + tid;  // < 49152
        int layer = t2 >> 14;
        int r = t2 & 16383;
        int ot = r >> 12;
        int kb = (r >> 9) & 7;
        int l = (r >> 3) & 63;
        int e = r & 7;
        int k = kb * 32 + (l >> 4) * 8 + e;
        int o = ot * 16 + (l & 15);
        int m = k >> 6;
        int kk = k & 63;
        const float* W = (layer == 0) ? W0 : (layer == 1) ? W1 : W2;
        wb[t2] = f2bf(W[(m * 64 + o) * 64 + kk]);
    } else if (b < 2071) {
        statz[(b - 2067) * 256 + tid] = make_int4(0, 0, 0, 0);  // 1024 int4
    } else {
        int e = (b - 2071) * 256 + tid;  // < NE
        int is64 = detect64((const unsigned int*)ei);
        int d = load_idx(ei, is64, NE + e);
        atomicAdd(&degi[d], 1);
    }
}

// ---------------------------------------------------------------------------
// scan: ONE block, 1024 threads. Coalesced load of degi into 120 KB LDS;
// thread-local exclusive prefix (30/thread) + block scan -> rowptr.
// ---------------------------------------------------------------------------
__global__ __launch_bounds__(1024) void k_scan(const int* __restrict__ degi,
                                               int* __restrict__ rowptr) {
    __shared__ int buf[30720];   // 120 KB
    __shared__ int sm[1024];
    int t = threadIdx.x;
    for (int i = t; i < 30720; i += 1024)
        buf[i] = (i < NN) ? degi[i] : 0;
    __syncthreads();
    const int PER = 30;
    int base = t * PER;
    int loc[PER];
    int sum = 0;
#pragma unroll
    for (int i = 0; i < PER; ++i) {
        loc[i] = sum;
        sum += buf[base + i];
    }
    sm[t] = sum;
    __syncthreads();
    for (int off = 1; off < 1024; off <<= 1) {
        int add = (t >= off) ? sm[t - off] : 0;
        __syncthreads();
        sm[t] += add;
        __syncthreads();
    }
    int tb = sm[t] - sum;
#pragma unroll
    for (int i = 0; i < PER; ++i) {
        int idx = base + i;
        if (idx < NN) rowptr[idx] = tb + loc[i];
    }
    if (t == 0) rowptr[NN] = NE;
}

// ---------------------------------------------------------------------------
// p0 (layer 0, no fold): p[n][m] = x[n,:] @ U0[m,:]  (x fp32)
// ---------------------------------------------------------------------------
__device__ __forceinline__ void dev_pk0(const float* __restrict__ h,
                                        const float* __restrict__ U,
                                        float* __restrict__ pout, int vb) {
    __shared__ float usc_s[4][64];
    int t = threadIdx.x;
    {
        int m = t >> 6, k = t & 63;
        usc_s[m][k] = U[m * 64 + k];
    }
    __syncthreads();
    int idx = vb * 256 + t;
    if (idx < NN * 4) {
        int n = idx >> 2, m = idx & 3;
        const float4* hn = reinterpret_cast<const float4*>(h) + (size_t)n * 16;
        const float* um = usc_s[m];
        float a = 0.0f;
#pragma unroll
        for (int j = 0; j < 16; ++j) {
            float4 hv = hn[j];
            a += hv.x * um[4 * j + 0] + hv.y * um[4 * j + 1] +
                 hv.z * um[4 * j + 2] + hv.w * um[4 * j + 3];
        }
        pout[idx] = a;
    }
}

// ---------------------------------------------------------------------------
// Fused: blocks 0..1874 scatter CSR (cursor-free atomicSub on degi, dead
// after scan); blocks 1875.. compute p0 = x@U0^T.
// ---------------------------------------------------------------------------
__global__ __launch_bounds__(256) void k_scatter_pk0(const void* __restrict__ ei,
                                                     const int* __restrict__ rowptr,
                                                     int* __restrict__ degi,
                                                     int* __restrict__ csr,
                                                     const float* __restrict__ x,
                                                     const float* __restrict__ U0,
                                                     float* __restrict__ p) {
    if (blockIdx.x < EBLK) {
        int is64 = detect64((const unsigned int*)ei);
        int e = blockIdx.x * 256 + threadIdx.x;
        int s = load_idx(ei, is64, e);
        int d = load_idx(ei, is64, NE + e);
        int old = atomicSub(&degi[d], 1);
        csr[rowptr[d] + old - 1] = s;
    } else {
        dev_pk0(x, U0, p, blockIdx.x - EBLK);
    }
}

// ---------------------------------------------------------------------------
// k_pk (fold layers): sums stats shards -> sc/sh; writes scv + cstv (block 0)
// and p[n][m] = hbf[n,:] @ (U[m,:]*sc), reading bf16 features directly.
// ---------------------------------------------------------------------------
__global__ __launch_bounds__(256) void k_pk(const ushort* __restrict__ hbf,
                                            const float* __restrict__ U,
                                            const float* __restrict__ statsS,
                                            const float* __restrict__ g,
                                            const float* __restrict__ W,
                                            const float* __restrict__ bt,
                                            float* __restrict__ pout,
                                            float* __restrict__ cstv_out,
                                            float* __restrict__ scv_out) {
    __shared__ float usc_s[4][64];
    __shared__ float sc_l[64];
    __shared__ float sh_l[64];
    int t = threadIdx.x;
    if (t < 64) {
        float s1 = 0.0f, s2 = 0.0f;
#pragma unroll
        for (int sh = 0; sh < NSHARD; ++sh) {
            s1 += statsS[sh * 128 + t];
            s2 += statsS[sh * 128 + 64 + t];
        }
        const float invN = 1.0f / (float)NN;
        float mu = s1 * invN;
        float var = s2 * invN - mu * mu;
        float sc = rsqrtf(var + BN_EPS) * g[t];
        sc_l[t] = sc;
        sh_l[t] = bt[t] - mu * sc;
        if (blockIdx.x == 0) scv_out[t] = sc;
    }
    __syncthreads();
    {
        int m = t >> 6, k = t & 63;
        usc_s[m][k] = U[m * 64 + k] * sc_l[k];
    }
    __syncthreads();
    int idx = blockIdx.x * 256 + t;
    if (idx < NN * 4) {
        int n = idx >> 2, m = idx & 3;
        const uint4* hn = reinterpret_cast<const uint4*>(hbf + (size_t)n * 64);
        const float* um = usc_s[m];
        float a = 0.0f;
#pragma unroll
        for (int j = 0; j < 8; ++j) {
            uint4 v = hn[j];
            a += bf2f((unsigned short)v.x) * um[8 * j + 0] +
                 bf2f((unsigned short)(v.x >> 16)) * um[8 * j + 1] +
                 bf2f((unsigned short)v.y) * um[8 * j + 2] +
                 bf2f((unsigned short)(v.y >> 16)) * um[8 * j + 3] +
                 bf2f((unsigned short)v.z) * um[8 * j + 4] +
                 bf2f((unsigned short)(v.z >> 16)) * um[8 * j + 5] +
                 bf2f((unsigned short)v.w) * um[8 * j + 6] +
                 bf2f((unsigned short)(v.w >> 16)) * um[8 * j + 7];
        }
        pout[idx] = a;
    }
    if (blockIdx.x == 0) {
        float s = 0.0f;
        const float* wr = W + (size_t)t * 64;
#pragma unroll 8
        for (int k = 0; k < 64; ++k) s += sh_l[k] * wr[k];
        cstv_out[t] = s;
    }
}

// ---------------------------------------------------------------------------
// Fused aggregate + GEMM, 8-wave gang (R9/R10-verified). 512 thr = 8 waves
// = 8 nodes/block. Phase A: wave per node, lane = channel; gather-aggregate,
// scale by invD*sc, bf16 z row -> LDS + zs. ONE barrier. Phase B: waves 0..3
// one 16-col o-tile each over 8 nodes (A rows 8..15 clamped/discarded);
// waves 4..7 exit. STATS layers store bf16 features; final layer fp32 d_out.
// ---------------------------------------------------------------------------
template <int FOLD, int STATS>
__global__ __launch_bounds__(512, 4) void k_fused(const int* __restrict__ rowptr,
                                                  const int* __restrict__ csr,
                                                  const float* __restrict__ p,
                                                  const ushort* __restrict__ hbf_in,
                                                  const float* __restrict__ cvec,
                                                  const float* __restrict__ scv,
                                                  const float* __restrict__ cstvg,
                                                  const ushort* __restrict__ wb,
                                                  const float* __restrict__ bvec,
                                                  float* __restrict__ hout,
                                                  ushort* __restrict__ hbfout,
                                                  float* __restrict__ stats_out) {
    __shared__ float4 attn_s[8][64];
    __shared__ int src_s[8][64];
    __shared__ ushort zrow[8][272];   // 544B stride: 16B-aligned rows
    __shared__ float4 zs_s[8];
    __shared__ float cstv_s[256];

    int t = threadIdx.x;
    int wid = t >> 6;
    int lane = t & 63;
    int n = blockIdx.x * 8 + wid;
    const float4* p4 = reinterpret_cast<const float4*>(p);

    if (FOLD && t < 256) cstv_s[t] = cstvg[t];

    float scl = FOLD ? scv[lane] : 1.0f;

    float4 cv = make_float4(cvec[0], cvec[1], cvec[2], cvec[3]);
    float smx = fmaxf(fmaxf(cv.x, cv.y), fmaxf(cv.z, cv.w));
    float se0 = __expf(cv.x - smx), se1 = __expf(cv.y - smx);
    float se2 = __expf(cv.z - smx), se3 = __expf(cv.w - smx);
    float sinv = 1.0f / (se0 + se1 + se2 + se3);
    float sl0 = se0 * sinv, sl1 = se1 * sinv, sl2 = se2 * sinv, sl3 = se3 * sinv;

    float4 pd = p4[n];
    float4 pdc = make_float4(pd.x + cv.x, pd.y + cv.y, pd.z + cv.z, pd.w + cv.w);
    float hs = bf2f(hbf_in[(unsigned)(n * 64 + lane)]);
    float acc0 = sl0 * hs, acc1 = sl1 * hs, acc2 = sl2 * hs, acc3 = sl3 * hs;
    float zt0 = sl0, zt1 = sl1, zt2 = sl2, zt3 = sl3;

    int start = rowptr[n];
    int end = rowptr[n + 1];
    for (int j = start; j < end; j += 64) {
        int chunk = end - j;
        if (chunk > 64) chunk = 64;
        if (lane < chunk) {
            int s = csr[j + lane];
            float4 q = p4[(unsigned)s];
            float l0 = pdc.x - q.x;
            float l1 = pdc.y - q.y;
            float l2 = pdc.z - q.z;
            float l3 = pdc.w - q.w;
            float mx = fmaxf(fmaxf(l0, l1), fmaxf(l2, l3));  // REQUIRED (R5 NaN)
            float e0 = __expf(l0 - mx);
            float e1 = __expf(l1 - mx);
            float e2 = __expf(l2 - mx);
            float e3 = __expf(l3 - mx);
            float inv = 1.0f / (e0 + e1 + e2 + e3);
            attn_s[wid][lane] = make_float4(e0 * inv, e1 * inv, e2 * inv, e3 * inv);
            src_s[wid][lane] = s;
        }
        int k = 0;
        for (; k + 4 <= chunk; k += 4) {
            float4 a0 = attn_s[wid][k];
            int s0 = src_s[wid][k];
            float4 a1 = attn_s[wid][k + 1];
            int s1 = src_s[wid][k + 1];
            float4 a2 = attn_s[wid][k + 2];
            int s2 = src_s[wid][k + 2];
            float4 a3 = attn_s[wid][k + 3];
            int s3 = src_s[wid][k + 3];
            float h0 = bf2f(hbf_in[(unsigned)(s0 * 64 + lane)]);
            float h1 = bf2f(hbf_in[(unsigned)(s1 * 64 + lane)]);
            float h2 = bf2f(hbf_in[(unsigned)(s2 * 64 + lane)]);
            float h3 = bf2f(hbf_in[(unsigned)(s3 * 64 + lane)]);
            acc0 += a0.x * h0 + a1.x * h1 + a2.x * h2 + a3.x * h3;
            acc1 += a0.y * h0 + a1.y * h1 + a2.y * h2 + a3.y * h3;
            acc2 += a0.z * h0 + a1.z * h1 + a2.z * h2 + a3.z * h3;
            acc3 += a0.w * h0 + a1.w * h1 + a2.w * h2 + a3.w * h3;
            zt0 += a0.x + a1.x + a2.x + a3.x;
            zt1 += a0.y + a1.y + a2.y + a3.y;
            zt2 += a0.z + a1.z + a2.z + a3.z;
            zt3 += a0.w + a1.w + a2.w + a3.w;
        }
        for (; k < chunk; ++k) {
            float4 a0 = attn_s[wid][k];
            int s0 = src_s[wid][k];
            float h0 = bf2f(hbf_in[(unsigned)(s0 * 64 + lane)]);
            acc0 += a0.x * h0;
            acc1 += a0.y * h0;
            acc2 += a0.z * h0;
            acc3 += a0.w * h0;
            zt0 += a0.x; zt1 += a0.y; zt2 += a0.z; zt3 += a0.w;
        }
    }

    float invD = 1.0f / (float)(end - start + 1);
    float s = invD * scl;
    {
        ushort* zr = &zrow[wid][0];
        zr[lane]       = f2bf(acc0 * s);
        zr[64 + lane]  = f2bf(acc1 * s);
        zr[128 + lane] = f2bf(acc2 * s);
        zr[192 + lane] = f2bf(acc3 * s);
        if (lane == 0)
            zs_s[wid] = make_float4(zt0 * invD, zt1 * invD, zt2 * invD, zt3 * invD);
    }
    __syncthreads();

    // ---- phase B: waves 0..3, one o-tile each; waves 4..7 done ----
    if (wid >= 4) return;

    int col = lane & 15;
    int grp = lane >> 4;
    int r = (col < 8) ? col : 7;        // A rows 8..15 clamped (discarded)
    const ushort* zr = &zrow[r][0];
    const ushort* wbp = wb + ((size_t)(wid * 8) * 64 + lane) * 8;
    f32x4 acc = {0.0f, 0.0f, 0.0f, 0.0f};
#pragma unroll
    for (int kb = 0; kb < 8; ++kb) {
        bf16x8 a = *reinterpret_cast<const bf16x8*>(zr + kb * 32 + grp * 8);
        bf16x8 b = *reinterpret_cast<const bf16x8*>(wbp + (size_t)kb * 512);
        acc = __builtin_amdgcn_mfma_f32_16x16x32_bf16(a, b, acc, 0, 0, 0);
    }

    // D layout: row=(lane>>4)*4+i, col=lane&15. Valid rows 0..7 -> grp<2.
    float ls = 0.0f, lq = 0.0f;
    if (grp < 2) {
        int n0 = blockIdx.x * 8;
        int o = wid * 16 + col;
        float bval = bvec[o];
#pragma unroll
        for (int i = 0; i < 4; ++i) {
            int nn = n0 + grp * 4 + i;
            float v = acc[i] + bval;
            if (FOLD) {
                float4 zv = zs_s[grp * 4 + i];
                v += zv.x * cstv_s[o] + zv.y * cstv_s[64 + o] +
                     zv.z * cstv_s[128 + o] + zv.w * cstv_s[192 + o];
            }
            if (STATS) {
                v = fmaxf(v, 0.0f);
                hbfout[(size_t)nn * 64 + o] = f2bf(v);
                ls += v;
                lq += v * v;
            } else {
                hout[(size_t)nn * 64 + o] = v;   // final layer: fp32 out
            }
        }
        if (STATS) {
            ls += __shfl_xor(ls, 16, 64);
            lq += __shfl_xor(lq, 16, 64);
            if (lane < 16) {
                float* so = stats_out + (blockIdx.x & (NSHARD - 1)) * 128;
                atomicAdd(&so[o], ls);
                atomicAdd(&so[64 + o], lq);
            }
        }
    }
}

// ---------------------------------------------------------------------------
// DIAGNOSTIC kernel (separate function so production codegen is untouched).
// MODE 0 = full phase A+B (same-grid baseline)
// MODE 1 = staging kept (LDS stores live), gather loop SKIPPED
// MODE 2 = staging skipped, gather-only (src masked in-bounds; attn garbage)
// Writes scratch outputs only. Timing read from rocprof per-dispatch rows.
// ---------------------------------------------------------------------------
template <int MODE>
__global__ __launch_bounds__(512, 4) void k_diag(const int* __restrict__ rowptr,
                                                 const int* __restrict__ csr,
                                                 const float* __restrict__ p,
                                                 const ushort* __restrict__ hbf_in,
                                                 const float* __restrict__ cvec,
                                                 const ushort* __restrict__ wb,
                                                 const float* __restrict__ bvec,
                                                 ushort* __restrict__ hbfout,
                                                 float* __restrict__ stats_out) {
    __shared__ float4 attn_s[8][64];
    __shared__ int src_s[8][64];
    __shared__ ushort zrow[8][272];
    __shared__ float4 zs_s[8];

    int t = threadIdx.x;
    int wid = t >> 6;
    int lane = t & 63;
    int n = blockIdx.x * 8 + wid;
    const float4* p4 = reinterpret_cast<const float4*>(p);

    float4 cv = make_float4(cvec[0], cvec[1], cvec[2], cvec[3]);
    float smx = fmaxf(fmaxf(cv.x, cv.y), fmaxf(cv.z, cv.w));
    float se0 = __expf(cv.x - smx), se1 = __expf(cv.y - smx);
    float se2 = __expf(cv.z - smx), se3 = __expf(cv.w - smx);
    float sinv = 1.0f / (se0 + se1 + se2 + se3);
    float sl0 = se0 * sinv, sl1 = se1 * sinv, sl2 = se2 * sinv, sl3 = se3 * sinv;

    float4 pd = p4[n];
    float4 pdc = make_float4(pd.x + cv.x, pd.y + cv.y, pd.z + cv.z, pd.w + cv.w);
    float hs = bf2f(hbf_in[(unsigned)(n * 64 + lane)]);
    float acc0 = sl0 * hs, acc1 = sl1 * hs, acc2 = sl2 * hs, acc3 = sl3 * hs;
    float zt0 = sl0, zt1 = sl1, zt2 = sl2, zt3 = sl3;

    int start = rowptr[n];
    int end = rowptr[n + 1];
    for (int j = start; j < end; j += 64) {
        int chunk = end - j;
        if (chunk > 64) chunk = 64;
        if (MODE != 2) {
            if (lane < chunk) {
                int s = csr[j + lane];
                float4 q = p4[(unsigned)s];
                float l0 = pdc.x - q.x;
                float l1 = pdc.y - q.y;
                float l2 = pdc.z - q.z;
                float l3 = pdc.w - q.w;
                float mx = fmaxf(fmaxf(l0, l1), fmaxf(l2, l3));
                float e0 = __expf(l0 - mx);
                float e1 = __expf(l1 - mx);
                float e2 = __expf(l2 - mx);
                float e3 = __expf(l3 - mx);
                float inv = 1.0f / (e0 + e1 + e2 + e3);
                attn_s[wid][lane] = make_float4(e0 * inv, e1 * inv, e2 * inv, e3 * inv);
                src_s[wid][lane] = s;
            }
        }
        if (MODE != 1) {
            int k = 0;
            for (; k + 4 <= chunk; k += 4) {
                float4 a0 = attn_s[wid][k];
                int s0 = src_s[wid][k];
                float4 a1 = attn_s[wid][k + 1];
                int s1 = src_s[wid][k + 1];
                float4 a2 = attn_s[wid][k + 2];
                int s2 = src_s[wid][k + 2];
                float4 a3 = attn_s[wid][k + 3];
                int s3 = src_s[wid][k + 3];
                if (MODE == 2) {  // stale LDS: mask indices in-bounds
                    s0 &= 16383; s1 &= 16383; s2 &= 16383; s3 &= 16383;
                }
                float h0 = bf2f(hbf_in[(unsigned)(s0 * 64 + lane)]);
                float h1 = bf2f(hbf_in[(unsigned)(s1 * 64 + lane)]);
                float h2 = bf2f(hbf_in[(unsigned)(s2 * 64 + lane)]);
                float h3 = bf2f(hbf_in[(unsigned)(s3 * 64 + lane)]);
                acc0 += a0.x * h0 + a1.x * h1 + a2.x * h2 + a3.x * h3;
                acc1 += a0.y * h0 + a1.y * h1 + a2.y * h2 + a3.y * h3;
                acc2 += a0.z * h0 + a1.z * h1 + a2.z * h2 + a3.z * h3;
                acc3 += a0.w * h0 + a1.w * h1 + a2.w * h2 + a3.w * h3;
                zt0 += a0.x + a1.x + a2.x + a3.x;
                zt1 += a0.y + a1.y + a2.y + a3.y;
                zt2 += a0.z + a1.z + a2.z + a3.z;
                zt3 += a0.w + a1.w + a2.w + a3.w;
            }
            for (; k < chunk; ++k) {
                float4 a0 = attn_s[wid][k];
                int s0 = src_s[wid][k];
                if (MODE == 2) s0 &= 16383;
                float h0 = bf2f(hbf_in[(unsigned)(s0 * 64 + lane)]);
                acc0 += a0.x * h0;
                acc1 += a0.y * h0;
                acc2 += a0.z * h0;
                acc3 += a0.w * h0;
                zt0 += a0.x; zt1 += a0.y; zt2 += a0.z; zt3 += a0.w;
            }
        }
    }

    float invD = 1.0f / (float)(end - start + 1);
    {
        ushort* zr = &zrow[wid][0];
        zr[lane]       = f2bf(acc0 * invD);
        zr[64 + lane]  = f2bf(acc1 * invD);
        zr[128 + lane] = f2bf(acc2 * invD);
        zr[192 + lane] = f2bf(acc3 * invD);
        if (lane == 0)
            zs_s[wid] = make_float4(zt0 * invD, zt1 * invD, zt2 * invD, zt3 * invD);
    }
    __syncthreads();
    (void)zs_s;

    if (wid >= 4) return;

    int col = lane & 15;
    int grp = lane >> 4;
    int r = (col < 8) ? col : 7;
    const ushort* zr = &zrow[r][0];
    const ushort* wbp = wb + ((size_t)(wid * 8) * 64 + lane) * 8;
    f32x4 acc = {0.0f, 0.0f, 0.0f, 0.0f};
#pragma unroll
    for (int kb = 0; kb < 8; ++kb) {
        bf16x8 a = *reinterpret_cast<const bf16x8*>(zr + kb * 32 + grp * 8);
        bf16x8 b = *reinterpret_cast<const bf16x8*>(wbp + (size_t)kb * 512);
        acc = __builtin_amdgcn_mfma_f32_16x16x32_bf16(a, b, acc, 0, 0, 0);
    }

    float ls = 0.0f, lq = 0.0f;
    if (grp < 2) {
        int n0 = blockIdx.x * 8;
        int o = wid * 16 + col;
        float bval = bvec[o];
#pragma unroll
        for (int i = 0; i < 4; ++i) {
            int nn = n0 + grp * 4 + i;
            float v = fmaxf(acc[i] + bval, 0.0f);
            hbfout[(size_t)nn * 64 + o] = f2bf(v);
            ls += v;
            lq += v * v;
        }
        ls += __shfl_xor(ls, 16, 64);
        lq += __shfl_xor(lq, 16, 64);
        if (lane < 16) {
            float* so = stats_out + (blockIdx.x & (NSHARD - 1)) * 128;
            atomicAdd(&so[o], ls);
            atomicAdd(&so[64 + o], lq);
        }
    }
}

extern "C" void kernel_launch(void* const* d_in, const int* in_sizes, int n_in,
                              void* d_out, int out_size, void* d_ws, size_t ws_size,
                              hipStream_t stream) {
    const float* x = (const float*)d_in[0];
    const void* ei = d_in[1];
    const float* W0 = (const float*)d_in[2];
    const float* U0 = (const float*)d_in[3];
    const float* c0 = (const float*)d_in[4];
    const float* b0 = (const float*)d_in[5];
    const float* g0 = (const float*)d_in[6];
    const float* bt0 = (const float*)d_in[7];
    const float* W1 = (const float*)d_in[8];
    const float* U1 = (const float*)d_in[9];
    const float* c1 = (const float*)d_in[10];
    const float* b1 = (const float*)d_in[11];
    const float* g1 = (const float*)d_in[12];
    const float* bt1 = (const float*)d_in[13];
    const float* W2 = (const float*)d_in[14];
    const float* U2 = (const float*)d_in[15];
    const float* c2 = (const float*)d_in[16];
    const float* b2 = (const float*)d_in[17];

    // workspace layout — all 16B-aligned
    ushort* xbf = (ushort*)d_ws;                      // NN*64 bf16
    ushort* hbfA = xbf + (size_t)NN * 64;             // NN*64 (double buffer A)
    ushort* hbfB = hbfA + (size_t)NN * 64;            // NN*64 (double buffer B)
    float* p = (float*)(hbfB + (size_t)NN * 64);      // NN*4
    float* cstv = p + (size_t)NN * 4;                 // 256
    float* scv = cstv + 256;                          // 64
    int* degi = (int*)(scv + 64);                     // NN (memset-zeroed)
    float* statsA = (float*)(degi + NN);              // 2*16*128 = 4096
    int* rowptr = (int*)(statsA + 4096);              // NN+4
    int* csr = rowptr + NN + 4;                       // NE
    ushort* wb = (ushort*)(csr + NE);                 // 3*16384 bf16
    float* dstats = (float*)(wb + 3 * 16384);         // 2048 diag scratch
    float* stats0 = statsA;
    float* stats1 = statsA + 2048;

    // 9 production stream ops (memset + 8 kernels) — R10-verified pipeline
    hipMemsetAsync(degi, 0, sizeof(int) * NN, stream);
    k_prep_hist<<<3946, 256, 0, stream>>>(x, W0, W1, W2, ei, xbf, wb,
                                          (int4*)statsA, degi);
    k_scan<<<1, 1024, 0, stream>>>(degi, rowptr);
    k_scatter_pk0<<<EBLK + PKBLK, 256, 0, stream>>>(ei, rowptr, degi, csr,
                                                    x, U0, p);

    // ---- layer 0: read xbf, write hbfA + stats0 shards ----
    k_fused<0, 1><<<FBLK, 512, 0, stream>>>(rowptr, csr, p, xbf, c0,
                                            nullptr, nullptr, wb, b0,
                                            nullptr, hbfA, stats0);
    // ---- layer 1: fold BN0; read hbfA, write hbfB + stats1 shards ----
    k_pk<<<PKBLK, 256, 0, stream>>>(hbfA, U1, stats0, g0, W1, bt0, p, cstv, scv);
    k_fused<1, 1><<<FBLK, 512, 0, stream>>>(rowptr, csr, p, hbfA, c1,
                                            scv, cstv, wb + 16384, b1,
                                            nullptr, hbfB, stats1);
    // ---- layer 2: fold BN1; read hbfB, write d_out (fp32) ----
    k_pk<<<PKBLK, 256, 0, stream>>>(hbfB, U2, stats1, g1, W2, bt1, p, cstv, scv);
    k_fused<1, 0><<<FBLK, 512, 0, stream>>>(rowptr, csr, p, hbfB, c2,
                                            scv, cstv, wb + 32768, b2,
                                            (float*)d_out, nullptr, nullptr);

    // ---- diagnostics (quarter grid, scratch outputs; rocprof-only) ----
    // d_out already written above; these touch only hbfA (dead) + dstats.
    k_diag<0><<<938, 512, 0, stream>>>(rowptr, csr, p, xbf, c0, wb, b0,
                                       hbfA, dstats);
    k_diag<1><<<938, 512, 0, stream>>>(rowptr, csr, p, xbf, c0, wb, b0,
                                       hbfA, dstats);
    k_diag<2><<<938, 512, 0, stream>>>(rowptr, csr, p, xbf, c0, wb, b0,
                                       hbfA, dstats);
}

// Round 14
// 265.201 us; speedup vs baseline: 1.2228x; 1.0631x over previous
//
#include <hip/hip_runtime.h>

#define NN 30000
#define NE 480000
#define BN_EPS 1e-5f
#define EBLK 1875     // NE/256 edge blocks
#define FBLK 3750     // fused blocks: 8 nodes each (512 thr = 8 waves)
#define PKBLK 469     // ceil(NN*4/256)
#define NSHARD 16     // stats atomic shards

typedef __attribute__((ext_vector_type(8))) short bf16x8;
typedef __attribute__((ext_vector_type(4))) float f32x4;

// ---------------------------------------------------------------------------
// bf16 helpers (RNE pack, cheap unpack)
// ---------------------------------------------------------------------------
__device__ __forceinline__ unsigned short f2bf(float x) {
    unsigned int u = __float_as_uint(x);
    return (unsigned short)((u + 0x7fffu + ((u >> 16) & 1u)) >> 16);
}
__device__ __forceinline__ float bf2f(unsigned short h) {
    return __uint_as_float(((unsigned int)h) << 16);
}

// int64-vs-int32 detect: odd 32-bit words of int64 indices < 2^31 are all 0.
__device__ __forceinline__ int detect64(const unsigned int* __restrict__ ei) {
    unsigned int v = ei[1] | ei[3] | ei[5] | ei[7] |
                     ei[9] | ei[11] | ei[13] | ei[15];
    return v == 0u;
}
__device__ __forceinline__ int load_idx(const void* ei, int is64, int pos) {
    if (is64) return (int)((const long long*)ei)[pos];
    return ((const int*)ei)[pos];
}

// ---------------------------------------------------------------------------
// prep ∥ hist (one dispatch; disjoint outputs; degi pre-zeroed by memset):
//   blocks [0,1875):    x -> xbf (bf16)
//   blocks [1875,2067): pack W0..W2 into MFMA B-fragment order (R5-verified)
//   blocks [2067,2071): zero stats shards (4096 floats)
//   blocks [2071,3946): dst-degree histogram
// ---------------------------------------------------------------------------
__global__ __launch_bounds__(256) void k_prep_hist(const float* __restrict__ x,
                                                   const float* __restrict__ W0,
                                                   const float* __restrict__ W1,
                                                   const float* __restrict__ W2,
                                                   const void* __restrict__ ei,
                                                   ushort* __restrict__ xbf,
                                                   ushort* __restrict__ wb,
                                                   int4* __restrict__ statz,
                                                   int* __restrict__ degi) {
    int b = blockIdx.x;
    int tid = threadIdx.x;
    if (b < 1875) {
        int t = b * 256 + tid;  // < 480000 = NN*64/4
        float4 v = reinterpret_cast<const float4*>(x)[t];
        ushort4 o;
        o.x = f2bf(v.x); o.y = f2bf(v.y); o.z = f2bf(v.z); o.w = f2bf(v.w);
        reinterpret_cast<ushort4*>(xbf)[t] = o;
    } else if (b < 2067) {
        int t2 = (b - 1875) * 256 + tid;  // < 49152
        int layer = t2 >> 14;
        int r = t2 & 16383;
        int ot = r >> 12;
        int kb = (r >> 9) & 7;
        int l = (r >> 3) & 63;
        int e = r & 7;
        int k = kb * 32 + (l >> 4) * 8 + e;
        int o = ot * 16 + (l & 15);
        int m = k >> 6;
        int kk = k & 63;
        const float* W = (layer == 0) ? W0 : (layer == 1) ? W1 : W2;
        wb[t2] = f2bf(W[(m * 64 + o) * 64 + kk]);
    } else if (b < 2071) {
        statz[(b - 2067) * 256 + tid] = make_int4(0, 0, 0, 0);  // 1024 int4
    } else {
        int e = (b - 2071) * 256 + tid;  // < NE
        int is64 = detect64((const unsigned int*)ei);
        int d = load_idx(ei, is64, NE + e);
        atomicAdd(&degi[d], 1);
    }
}

// ---------------------------------------------------------------------------
// scan: ONE block, 1024 threads. Coalesced load of degi into 120 KB LDS;
// thread-local exclusive prefix (30/thread) + block scan -> rowptr.
// ---------------------------------------------------------------------------
__global__ __launch_bounds__(1024) void k_scan(const int* __restrict__ degi,
                                               int* __restrict__ rowptr) {
    __shared__ int buf[30720];   // 120 KB
    __shared__ int sm[1024];
    int t = threadIdx.x;
    for (int i = t; i < 30720; i += 1024)
        buf[i] = (i < NN) ? degi[i] : 0;
    __syncthreads();
    const int PER = 30;
    int base = t * PER;
    int loc[PER];
    int sum = 0;
#pragma unroll
    for (int i = 0; i < PER; ++i) {
        loc[i] = sum;
        sum += buf[base + i];
    }
    sm[t] = sum;
    __syncthreads();
    for (int off = 1; off < 1024; off <<= 1) {
        int add = (t >= off) ? sm[t - off] : 0;
        __syncthreads();
        sm[t] += add;
        __syncthreads();
    }
    int tb = sm[t] - sum;
#pragma unroll
    for (int i = 0; i < PER; ++i) {
        int idx = base + i;
        if (idx < NN) rowptr[idx] = tb + loc[i];
    }
    if (t == 0) rowptr[NN] = NE;
}

// ---------------------------------------------------------------------------
// p0 (layer 0, no fold): p[n][m] = x[n,:] @ U0[m,:]  (x fp32)
// ---------------------------------------------------------------------------
__device__ __forceinline__ void dev_pk0(const float* __restrict__ h,
                                        const float* __restrict__ U,
                                        float* __restrict__ pout, int vb) {
    __shared__ float usc_s[4][64];
    int t = threadIdx.x;
    {
        int m = t >> 6, k = t & 63;
        usc_s[m][k] = U[m * 64 + k];
    }
    __syncthreads();
    int idx = vb * 256 + t;
    if (idx < NN * 4) {
        int n = idx >> 2, m = idx & 3;
        const float4* hn = reinterpret_cast<const float4*>(h) + (size_t)n * 16;
        const float* um = usc_s[m];
        float a = 0.0f;
#pragma unroll
        for (int j = 0; j < 16; ++j) {
            float4 hv = hn[j];
            a += hv.x * um[4 * j + 0] + hv.y * um[4 * j + 1] +
                 hv.z * um[4 * j + 2] + hv.w * um[4 * j + 3];
        }
        pout[idx] = a;
    }
}

// ---------------------------------------------------------------------------
// Fused: blocks 0..1874 scatter CSR (cursor-free atomicSub on degi, dead
// after scan); blocks 1875.. compute p0 = x@U0^T.
// ---------------------------------------------------------------------------
__global__ __launch_bounds__(256) void k_scatter_pk0(const void* __restrict__ ei,
                                                     const int* __restrict__ rowptr,
                                                     int* __restrict__ degi,
                                                     int* __restrict__ csr,
                                                     const float* __restrict__ x,
                                                     const float* __restrict__ U0,
                                                     float* __restrict__ p) {
    if (blockIdx.x < EBLK) {
        int is64 = detect64((const unsigned int*)ei);
        int e = blockIdx.x * 256 + threadIdx.x;
        int s = load_idx(ei, is64, e);
        int d = load_idx(ei, is64, NE + e);
        int old = atomicSub(&degi[d], 1);
        csr[rowptr[d] + old - 1] = s;
    } else {
        dev_pk0(x, U0, p, blockIdx.x - EBLK);
    }
}

// ---------------------------------------------------------------------------
// k_pk (fold layers): sums stats shards -> sc/sh; writes scv + cstv (block 0)
// and p[n][m] = hbf[n,:] @ (U[m,:]*sc), reading bf16 features directly.
// ---------------------------------------------------------------------------
__global__ __launch_bounds__(256) void k_pk(const ushort* __restrict__ hbf,
                                            const float* __restrict__ U,
                                            const float* __restrict__ statsS,
                                            const float* __restrict__ g,
                                            const float* __restrict__ W,
                                            const float* __restrict__ bt,
                                            float* __restrict__ pout,
                                            float* __restrict__ cstv_out,
                                            float* __restrict__ scv_out) {
    __shared__ float usc_s[4][64];
    __shared__ float sc_l[64];
    __shared__ float sh_l[64];
    int t = threadIdx.x;
    if (t < 64) {
        float s1 = 0.0f, s2 = 0.0f;
#pragma unroll
        for (int sh = 0; sh < NSHARD; ++sh) {
            s1 += statsS[sh * 128 + t];
            s2 += statsS[sh * 128 + 64 + t];
        }
        const float invN = 1.0f / (float)NN;
        float mu = s1 * invN;
        float var = s2 * invN - mu * mu;
        float sc = rsqrtf(var + BN_EPS) * g[t];
        sc_l[t] = sc;
        sh_l[t] = bt[t] - mu * sc;
        if (blockIdx.x == 0) scv_out[t] = sc;
    }
    __syncthreads();
    {
        int m = t >> 6, k = t & 63;
        usc_s[m][k] = U[m * 64 + k] * sc_l[k];
    }
    __syncthreads();
    int idx = blockIdx.x * 256 + t;
    if (idx < NN * 4) {
        int n = idx >> 2, m = idx & 3;
        const uint4* hn = reinterpret_cast<const uint4*>(hbf + (size_t)n * 64);
        const float* um = usc_s[m];
        float a = 0.0f;
#pragma unroll
        for (int j = 0; j < 8; ++j) {
            uint4 v = hn[j];
            a += bf2f((unsigned short)v.x) * um[8 * j + 0] +
                 bf2f((unsigned short)(v.x >> 16)) * um[8 * j + 1] +
                 bf2f((unsigned short)v.y) * um[8 * j + 2] +
                 bf2f((unsigned short)(v.y >> 16)) * um[8 * j + 3] +
                 bf2f((unsigned short)v.z) * um[8 * j + 4] +
                 bf2f((unsigned short)(v.z >> 16)) * um[8 * j + 5] +
                 bf2f((unsigned short)v.w) * um[8 * j + 6] +
                 bf2f((unsigned short)(v.w >> 16)) * um[8 * j + 7];
        }
        pout[idx] = a;
    }
    if (blockIdx.x == 0) {
        float s = 0.0f;
        const float* wr = W + (size_t)t * 64;
#pragma unroll 8
        for (int k = 0; k < 64; ++k) s += sh_l[k] * wr[k];
        cstv_out[t] = s;
    }
}

// ---------------------------------------------------------------------------
// Fused aggregate + GEMM, 8-wave gang. NEW: EDGE-PARALLEL STAGING.
// The block's 8 nodes own a CONTIGUOUS csr slice [rowptr[n0], rowptr[n0+8]).
// All 512 threads stage one edge slot each (coalesced csr read, p gather,
// 4-head softmax) into flat LDS; then each wave aggregates its own node's
// edges from the flat arrays (lane = channel, broadcast attn/src).
// Replaces the old per-wave staging where only deg(~16)/64 lanes worked.
// Multi-round loop handles E_b > 512 (never for this input, but correct).
// Phase B (MFMA o-tiles) and stats identical to R9/R10-verified code.
// ---------------------------------------------------------------------------
template <int FOLD, int STATS>
__global__ __launch_bounds__(512, 4) void k_fused(const int* __restrict__ rowptr,
                                                  const int* __restrict__ csr,
                                                  const float* __restrict__ p,
                                                  const ushort* __restrict__ hbf_in,
                                                  const float* __restrict__ cvec,
                                                  const float* __restrict__ scv,
                                                  const float* __restrict__ cstvg,
                                                  const ushort* __restrict__ wb,
                                                  const float* __restrict__ bvec,
                                                  float* __restrict__ hout,
                                                  ushort* __restrict__ hbfout,
                                                  float* __restrict__ stats_out) {
    __shared__ int r_s[9];
    __shared__ float4 pdc_s[8];
    __shared__ float4 attn_f[512];    // 8 KB flat attn
    __shared__ int src_f[512];        // 2 KB flat src
    __shared__ ushort zrow[8][272];   // 544B stride: 16B-aligned rows
    __shared__ float4 zs_s[8];
    __shared__ float cstv_s[256];

    int t = threadIdx.x;
    int wid = t >> 6;
    int lane = t & 63;
    int n0 = blockIdx.x * 8;
    int n = n0 + wid;
    const float4* p4 = reinterpret_cast<const float4*>(p);

    if (FOLD && t < 256) cstv_s[t] = cstvg[t];

    float4 cv = make_float4(cvec[0], cvec[1], cvec[2], cvec[3]);
    if (t < 9) r_s[t] = rowptr[n0 + t];
    if (t >= 16 && t < 24) {
        int i = t - 16;
        float4 pd = p4[n0 + i];
        pdc_s[i] = make_float4(pd.x + cv.x, pd.y + cv.y, pd.z + cv.z, pd.w + cv.w);
    }

    float scl = FOLD ? scv[lane] : 1.0f;

    // self-loop attention = softmax(c), node-independent
    float smx = fmaxf(fmaxf(cv.x, cv.y), fmaxf(cv.z, cv.w));
    float se0 = __expf(cv.x - smx), se1 = __expf(cv.y - smx);
    float se2 = __expf(cv.z - smx), se3 = __expf(cv.w - smx);
    float sinv = 1.0f / (se0 + se1 + se2 + se3);
    float sl0 = se0 * sinv, sl1 = se1 * sinv, sl2 = se2 * sinv, sl3 = se3 * sinv;

    float hs = bf2f(hbf_in[(unsigned)(n * 64 + lane)]);
    float acc0 = sl0 * hs, acc1 = sl1 * hs, acc2 = sl2 * hs, acc3 = sl3 * hs;
    float zt0 = sl0, zt1 = sl1, zt2 = sl2, zt3 = sl3;

    __syncthreads();
    int base = r_s[0];
    int endb = r_s[8];
    int Eb = endb - base;
    int gs = r_s[wid];
    int ge = r_s[wid + 1];

    for (int eb = 0; eb < Eb; eb += 512) {
        int j = base + eb + t;
        if (j < endb) {
            // which of the 8 nodes owns slot j (r_s broadcast reads)
            int i = 0;
#pragma unroll
            for (int qq = 1; qq < 8; ++qq) i += (j >= r_s[qq]);
            int s = csr[j];                    // coalesced across block
            float4 q = p4[(unsigned)s];        // 16B gather (L2)
            float4 pdc = pdc_s[i];
            float l0 = pdc.x - q.x;
            float l1 = pdc.y - q.y;
            float l2 = pdc.z - q.z;
            float l3 = pdc.w - q.w;
            float mx = fmaxf(fmaxf(l0, l1), fmaxf(l2, l3));  // REQUIRED (R5 NaN)
            float e0 = __expf(l0 - mx);
            float e1 = __expf(l1 - mx);
            float e2 = __expf(l2 - mx);
            float e3 = __expf(l3 - mx);
            float inv = 1.0f / (e0 + e1 + e2 + e3);
            attn_f[t] = make_float4(e0 * inv, e1 * inv, e2 * inv, e3 * inv);
            src_f[t] = s;
        }
        __syncthreads();

        // aggregate this wave's node over the staged window
        int from = gs > base + eb ? gs : base + eb;
        int to = ge < base + eb + 512 ? ge : base + eb + 512;
        int li = from - base - eb;
        int cnt = to - from;
        int k = 0;
        for (; k + 4 <= cnt; k += 4) {
            float4 a0 = attn_f[li + k];
            int s0 = src_f[li + k];
            float4 a1 = attn_f[li + k + 1];
            int s1 = src_f[li + k + 1];
            float4 a2 = attn_f[li + k + 2];
            int s2 = src_f[li + k + 2];
            float4 a3 = attn_f[li + k + 3];
            int s3 = src_f[li + k + 3];
            float h0 = bf2f(hbf_in[(unsigned)(s0 * 64 + lane)]);
            float h1 = bf2f(hbf_in[(unsigned)(s1 * 64 + lane)]);
            float h2 = bf2f(hbf_in[(unsigned)(s2 * 64 + lane)]);
            float h3 = bf2f(hbf_in[(unsigned)(s3 * 64 + lane)]);
            acc0 += a0.x * h0 + a1.x * h1 + a2.x * h2 + a3.x * h3;
            acc1 += a0.y * h0 + a1.y * h1 + a2.y * h2 + a3.y * h3;
            acc2 += a0.z * h0 + a1.z * h1 + a2.z * h2 + a3.z * h3;
            acc3 += a0.w * h0 + a1.w * h1 + a2.w * h2 + a3.w * h3;
            zt0 += a0.x + a1.x + a2.x + a3.x;
            zt1 += a0.y + a1.y + a2.y + a3.y;
            zt2 += a0.z + a1.z + a2.z + a3.z;
            zt3 += a0.w + a1.w + a2.w + a3.w;
        }
        for (; k < cnt; ++k) {
            float4 a0 = attn_f[li + k];
            int s0 = src_f[li + k];
            float h0 = bf2f(hbf_in[(unsigned)(s0 * 64 + lane)]);
            acc0 += a0.x * h0;
            acc1 += a0.y * h0;
            acc2 += a0.z * h0;
            acc3 += a0.w * h0;
            zt0 += a0.x; zt1 += a0.y; zt2 += a0.z; zt3 += a0.w;
        }
        __syncthreads();   // protect flat arrays before next round (if any)
    }

    float invD = 1.0f / (float)(ge - gs + 1);
    float s = invD * scl;
    {
        ushort* zr = &zrow[wid][0];
        zr[lane]       = f2bf(acc0 * s);
        zr[64 + lane]  = f2bf(acc1 * s);
        zr[128 + lane] = f2bf(acc2 * s);
        zr[192 + lane] = f2bf(acc3 * s);
        if (lane == 0)
            zs_s[wid] = make_float4(zt0 * invD, zt1 * invD, zt2 * invD, zt3 * invD);
    }
    __syncthreads();

    // ---- phase B: waves 0..3, one o-tile each; waves 4..7 done ----
    if (wid >= 4) return;

    int col = lane & 15;
    int grp = lane >> 4;
    int r = (col < 8) ? col : 7;        // A rows 8..15 clamped (discarded)
    const ushort* zr = &zrow[r][0];
    const ushort* wbp = wb + ((size_t)(wid * 8) * 64 + lane) * 8;
    f32x4 acc = {0.0f, 0.0f, 0.0f, 0.0f};
#pragma unroll
    for (int kb = 0; kb < 8; ++kb) {
        bf16x8 a = *reinterpret_cast<const bf16x8*>(zr + kb * 32 + grp * 8);
        bf16x8 b = *reinterpret_cast<const bf16x8*>(wbp + (size_t)kb * 512);
        acc = __builtin_amdgcn_mfma_f32_16x16x32_bf16(a, b, acc, 0, 0, 0);
    }

    // D layout: row=(lane>>4)*4+i, col=lane&15. Valid rows 0..7 -> grp<2.
    float ls = 0.0f, lq = 0.0f;
    if (grp < 2) {
        int o = wid * 16 + col;
        float bval = bvec[o];
#pragma unroll
        for (int i = 0; i < 4; ++i) {
            int nn = n0 + grp * 4 + i;
            float v = acc[i] + bval;
            if (FOLD) {
                float4 zv = zs_s[grp * 4 + i];
                v += zv.x * cstv_s[o] + zv.y * cstv_s[64 + o] +
                     zv.z * cstv_s[128 + o] + zv.w * cstv_s[192 + o];
            }
            if (STATS) {
                v = fmaxf(v, 0.0f);
                hbfout[(size_t)nn * 64 + o] = f2bf(v);
                ls += v;
                lq += v * v;
            } else {
                hout[(size_t)nn * 64 + o] = v;   // final layer: fp32 out
            }
        }
        if (STATS) {
            ls += __shfl_xor(ls, 16, 64);
            lq += __shfl_xor(lq, 16, 64);
            if (lane < 16) {
                float* so = stats_out + (blockIdx.x & (NSHARD - 1)) * 128;
                atomicAdd(&so[o], ls);
                atomicAdd(&so[64 + o], lq);
            }
        }
    }
}

extern "C" void kernel_launch(void* const* d_in, const int* in_sizes, int n_in,
                              void* d_out, int out_size, void* d_ws, size_t ws_size,
                              hipStream_t stream) {
    const float* x = (const float*)d_in[0];
    const void* ei = d_in[1];
    const float* W0 = (const float*)d_in[2];
    const float* U0 = (const float*)d_in[3];
    const float* c0 = (const float*)d_in[4];
    const float* b0 = (const float*)d_in[5];
    const float* g0 = (const float*)d_in[6];
    const float* bt0 = (const float*)d_in[7];
    const float* W1 = (const float*)d_in[8];
    const float* U1 = (const float*)d_in[9];
    const float* c1 = (const float*)d_in[10];
    const float* b1 = (const float*)d_in[11];
    const float* g1 = (const float*)d_in[12];
    const float* bt1 = (const float*)d_in[13];
    const float* W2 = (const float*)d_in[14];
    const float* U2 = (const float*)d_in[15];
    const float* c2 = (const float*)d_in[16];
    const float* b2 = (const float*)d_in[17];

    // workspace layout — all 16B-aligned
    ushort* xbf = (ushort*)d_ws;                      // NN*64 bf16
    ushort* hbfA = xbf + (size_t)NN * 64;             // NN*64 (double buffer A)
    ushort* hbfB = hbfA + (size_t)NN * 64;            // NN*64 (double buffer B)
    float* p = (float*)(hbfB + (size_t)NN * 64);      // NN*4
    float* cstv = p + (size_t)NN * 4;                 // 256
    float* scv = cstv + 256;                          // 64
    int* degi = (int*)(scv + 64);                     // NN (memset-zeroed)
    float* statsA = (float*)(degi + NN);              // 2*16*128 = 4096
    int* rowptr = (int*)(statsA + 4096);              // NN+4
    int* csr = rowptr + NN + 4;                       // NE
    ushort* wb = (ushort*)(csr + NE);                 // 3*16384 bf16
    float* stats0 = statsA;
    float* stats1 = statsA + 2048;

    // 9 stream ops (memset + 8 kernels) — R10 pipeline, new fused staging
    hipMemsetAsync(degi, 0, sizeof(int) * NN, stream);
    k_prep_hist<<<3946, 256, 0, stream>>>(x, W0, W1, W2, ei, xbf, wb,
                                          (int4*)statsA, degi);
    k_scan<<<1, 1024, 0, stream>>>(degi, rowptr);
    k_scatter_pk0<<<EBLK + PKBLK, 256, 0, stream>>>(ei, rowptr, degi, csr,
                                                    x, U0, p);

    // ---- layer 0: read xbf, write hbfA + stats0 shards ----
    k_fused<0, 1><<<FBLK, 512, 0, stream>>>(rowptr, csr, p, xbf, c0,
                                            nullptr, nullptr, wb, b0,
                                            nullptr, hbfA, stats0);
    // ---- layer 1: fold BN0; read hbfA, write hbfB + stats1 shards ----
    k_pk<<<PKBLK, 256, 0, stream>>>(hbfA, U1, stats0, g0, W1, bt0, p, cstv, scv);
    k_fused<1, 1><<<FBLK, 512, 0, stream>>>(rowptr, csr, p, hbfA, c1,
                                            scv, cstv, wb + 16384, b1,
                                            nullptr, hbfB, stats1);
    // ---- layer 2: fold BN1; read hbfB, write d_out (fp32) ----
    k_pk<<<PKBLK, 256, 0, stream>>>(hbfB, U2, stats1, g1, W2, bt1, p, cstv, scv);
    k_fused<1, 0><<<FBLK, 512, 0, stream>>>(rowptr, csr, p, hbfB, c2,
                                            scv, cstv, wb + 32768, b2,
                                            (float*)d_out, nullptr, nullptr);
}

// Round 15
// 265.045 us; speedup vs baseline: 1.2235x; 1.0006x over previous
//
#include <hip/hip_runtime.h>

#define NN 30000
#define NE 480000
#define BN_EPS 1e-5f
#define EBLK 1875     // NE/256 edge blocks
#define FBLK 3750     // fused blocks: 8 nodes each (512 thr = 8 waves)
#define PKBLK 469     // ceil(NN*4/256)
#define NSHARD 16     // stats atomic shards

typedef __attribute__((ext_vector_type(8))) short bf16x8;
typedef __attribute__((ext_vector_type(4))) float f32x4;

// ---------------------------------------------------------------------------
// bf16 helpers (RNE pack, cheap unpack)
// ---------------------------------------------------------------------------
__device__ __forceinline__ unsigned short f2bf(float x) {
    unsigned int u = __float_as_uint(x);
    return (unsigned short)((u + 0x7fffu + ((u >> 16) & 1u)) >> 16);
}
__device__ __forceinline__ float bf2f(unsigned short h) {
    return __uint_as_float(((unsigned int)h) << 16);
}

// int64-vs-int32 detect: odd 32-bit words of int64 indices < 2^31 are all 0.
__device__ __forceinline__ int detect64(const unsigned int* __restrict__ ei) {
    unsigned int v = ei[1] | ei[3] | ei[5] | ei[7] |
                     ei[9] | ei[11] | ei[13] | ei[15];
    return v == 0u;
}
__device__ __forceinline__ int load_idx(const void* ei, int is64, int pos) {
    if (is64) return (int)((const long long*)ei)[pos];
    return ((const int*)ei)[pos];
}

// ---------------------------------------------------------------------------
// prep ∥ hist (one dispatch; disjoint outputs; degi pre-zeroed by memset):
//   blocks [0,1875):    x -> xbf (bf16)
//   blocks [1875,2067): pack W0..W2 into MFMA B-fragment order (R5-verified)
//   blocks [2067,2071): zero stats shards (4096 floats)
//   blocks [2071,3946): dst-degree histogram
// ---------------------------------------------------------------------------
__global__ __launch_bounds__(256) void k_prep_hist(const float* __restrict__ x,
                                                   const float* __restrict__ W0,
                                                   const float* __restrict__ W1,
                                                   const float* __restrict__ W2,
                                                   const void* __restrict__ ei,
                                                   ushort* __restrict__ xbf,
                                                   ushort* __restrict__ wb,
                                                   int4* __restrict__ statz,
                                                   int* __restrict__ degi) {
    int b = blockIdx.x;
    int tid = threadIdx.x;
    if (b < 1875) {
        int t = b * 256 + tid;  // < 480000 = NN*64/4
        float4 v = reinterpret_cast<const float4*>(x)[t];
        ushort4 o;
        o.x = f2bf(v.x); o.y = f2bf(v.y); o.z = f2bf(v.z); o.w = f2bf(v.w);
        reinterpret_cast<ushort4*>(xbf)[t] = o;
    } else if (b < 2067) {
        int t2 = (b - 1875) * 256 + tid;  // < 49152
        int layer = t2 >> 14;
        int r = t2 & 16383;
        int ot = r >> 12;
        int kb = (r >> 9) & 7;
        int l = (r >> 3) & 63;
        int e = r & 7;
        int k = kb * 32 + (l >> 4) * 8 + e;
        int o = ot * 16 + (l & 15);
        int m = k >> 6;
        int kk = k & 63;
        const float* W = (layer == 0) ? W0 : (layer == 1) ? W1 : W2;
        wb[t2] = f2bf(W[(m * 64 + o) * 64 + kk]);
    } else if (b < 2071) {
        statz[(b - 2067) * 256 + tid] = make_int4(0, 0, 0, 0);  // 1024 int4
    } else {
        int e = (b - 2071) * 256 + tid;  // < NE
        int is64 = detect64((const unsigned int*)ei);
        int d = load_idx(ei, is64, NE + e);
        atomicAdd(&degi[d], 1);
    }
}

// ---------------------------------------------------------------------------
// scan: ONE block, 1024 threads. Coalesced load of degi into 120 KB LDS;
// thread-local exclusive prefix (30/thread) + block scan -> rowptr.
// ---------------------------------------------------------------------------
__global__ __launch_bounds__(1024) void k_scan(const int* __restrict__ degi,
                                               int* __restrict__ rowptr) {
    __shared__ int buf[30720];   // 120 KB
    __shared__ int sm[1024];
    int t = threadIdx.x;
    for (int i = t; i < 30720; i += 1024)
        buf[i] = (i < NN) ? degi[i] : 0;
    __syncthreads();
    const int PER = 30;
    int base = t * PER;
    int loc[PER];
    int sum = 0;
#pragma unroll
    for (int i = 0; i < PER; ++i) {
        loc[i] = sum;
        sum += buf[base + i];
    }
    sm[t] = sum;
    __syncthreads();
    for (int off = 1; off < 1024; off <<= 1) {
        int add = (t >= off) ? sm[t - off] : 0;
        __syncthreads();
        sm[t] += add;
        __syncthreads();
    }
    int tb = sm[t] - sum;
#pragma unroll
    for (int i = 0; i < PER; ++i) {
        int idx = base + i;
        if (idx < NN) rowptr[idx] = tb + loc[i];
    }
    if (t == 0) rowptr[NN] = NE;
}

// ---------------------------------------------------------------------------
// p0 (layer 0, no fold): p[n][m] = x[n,:] @ U0[m,:]  (x fp32)
// ---------------------------------------------------------------------------
__device__ __forceinline__ void dev_pk0(const float* __restrict__ h,
                                        const float* __restrict__ U,
                                        float* __restrict__ pout, int vb) {
    __shared__ float usc_s[4][64];
    int t = threadIdx.x;
    {
        int m = t >> 6, k = t & 63;
        usc_s[m][k] = U[m * 64 + k];
    }
    __syncthreads();
    int idx = vb * 256 + t;
    if (idx < NN * 4) {
        int n = idx >> 2, m = idx & 3;
        const float4* hn = reinterpret_cast<const float4*>(h) + (size_t)n * 16;
        const float* um = usc_s[m];
        float a = 0.0f;
#pragma unroll
        for (int j = 0; j < 16; ++j) {
            float4 hv = hn[j];
            a += hv.x * um[4 * j + 0] + hv.y * um[4 * j + 1] +
                 hv.z * um[4 * j + 2] + hv.w * um[4 * j + 3];
        }
        pout[idx] = a;
    }
}

// ---------------------------------------------------------------------------
// Fused: blocks 0..1874 scatter CSR (cursor-free atomicSub on degi, dead
// after scan); blocks 1875.. compute p0 = x@U0^T.
// ---------------------------------------------------------------------------
__global__ __launch_bounds__(256) void k_scatter_pk0(const void* __restrict__ ei,
                                                     const int* __restrict__ rowptr,
                                                     int* __restrict__ degi,
                                                     int* __restrict__ csr,
                                                     const float* __restrict__ x,
                                                     const float* __restrict__ U0,
                                                     float* __restrict__ p) {
    if (blockIdx.x < EBLK) {
        int is64 = detect64((const unsigned int*)ei);
        int e = blockIdx.x * 256 + threadIdx.x;
        int s = load_idx(ei, is64, e);
        int d = load_idx(ei, is64, NE + e);
        int old = atomicSub(&degi[d], 1);
        csr[rowptr[d] + old - 1] = s;
    } else {
        dev_pk0(x, U0, p, blockIdx.x - EBLK);
    }
}

// ---------------------------------------------------------------------------
// k_pk (fold layers): sums stats shards -> sc/sh; writes scv + cstv (block 0)
// and p[n][m] = hbf[n,:] @ (U[m,:]*sc), reading bf16 features directly.
// ---------------------------------------------------------------------------
__global__ __launch_bounds__(256) void k_pk(const ushort* __restrict__ hbf,
                                            const float* __restrict__ U,
                                            const float* __restrict__ statsS,
                                            const float* __restrict__ g,
                                            const float* __restrict__ W,
                                            const float* __restrict__ bt,
                                            float* __restrict__ pout,
                                            float* __restrict__ cstv_out,
                                            float* __restrict__ scv_out) {
    __shared__ float usc_s[4][64];
    __shared__ float sc_l[64];
    __shared__ float sh_l[64];
    int t = threadIdx.x;
    if (t < 64) {
        float s1 = 0.0f, s2 = 0.0f;
#pragma unroll
        for (int sh = 0; sh < NSHARD; ++sh) {
            s1 += statsS[sh * 128 + t];
            s2 += statsS[sh * 128 + 64 + t];
        }
        const float invN = 1.0f / (float)NN;
        float mu = s1 * invN;
        float var = s2 * invN - mu * mu;
        float sc = rsqrtf(var + BN_EPS) * g[t];
        sc_l[t] = sc;
        sh_l[t] = bt[t] - mu * sc;
        if (blockIdx.x == 0) scv_out[t] = sc;
    }
    __syncthreads();
    {
        int m = t >> 6, k = t & 63;
        usc_s[m][k] = U[m * 64 + k] * sc_l[k];
    }
    __syncthreads();
    int idx = blockIdx.x * 256 + t;
    if (idx < NN * 4) {
        int n = idx >> 2, m = idx & 3;
        const uint4* hn = reinterpret_cast<const uint4*>(hbf + (size_t)n * 64);
        const float* um = usc_s[m];
        float a = 0.0f;
#pragma unroll
        for (int j = 0; j < 8; ++j) {
            uint4 v = hn[j];
            a += bf2f((unsigned short)v.x) * um[8 * j + 0] +
                 bf2f((unsigned short)(v.x >> 16)) * um[8 * j + 1] +
                 bf2f((unsigned short)v.y) * um[8 * j + 2] +
                 bf2f((unsigned short)(v.y >> 16)) * um[8 * j + 3] +
                 bf2f((unsigned short)v.z) * um[8 * j + 4] +
                 bf2f((unsigned short)(v.z >> 16)) * um[8 * j + 5] +
                 bf2f((unsigned short)v.w) * um[8 * j + 6] +
                 bf2f((unsigned short)(v.w >> 16)) * um[8 * j + 7];
        }
        pout[idx] = a;
    }
    if (blockIdx.x == 0) {
        float s = 0.0f;
        const float* wr = W + (size_t)t * 64;
#pragma unroll 8
        for (int k = 0; k < 64; ++k) s += sh_l[k] * wr[k];
        cstv_out[t] = s;
    }
}

// ---------------------------------------------------------------------------
// Fused aggregate + GEMM, 8-wave gang, edge-parallel staging (R14), plus
// CACHE STEERING: during this kernel the REUSE set is hbf_in (3.84 MB,
// gathered ~17x per row) + p (0.5 MB) — together they fit the 4 MB per-XCD
// L2 ONLY if the streaming traffic doesn't evict them. So:
//   * csr reads     -> nontemporal LOAD  (pure stream, read once)
//   * hbfout/hout   -> nontemporal STORE (write-once, re-read next dispatch)
// This keeps hbf gathers at L2 (~200cy) instead of L3 (~500+cy) — the
// remaining theory after straggler/gather-count/staging were falsified.
// ---------------------------------------------------------------------------
template <int FOLD, int STATS>
__global__ __launch_bounds__(512, 4) void k_fused(const int* __restrict__ rowptr,
                                                  const int* __restrict__ csr,
                                                  const float* __restrict__ p,
                                                  const ushort* __restrict__ hbf_in,
                                                  const float* __restrict__ cvec,
                                                  const float* __restrict__ scv,
                                                  const float* __restrict__ cstvg,
                                                  const ushort* __restrict__ wb,
                                                  const float* __restrict__ bvec,
                                                  float* __restrict__ hout,
                                                  ushort* __restrict__ hbfout,
                                                  float* __restrict__ stats_out) {
    __shared__ int r_s[9];
    __shared__ float4 pdc_s[8];
    __shared__ float4 attn_f[512];    // 8 KB flat attn
    __shared__ int src_f[512];        // 2 KB flat src
    __shared__ ushort zrow[8][272];   // 544B stride: 16B-aligned rows
    __shared__ float4 zs_s[8];
    __shared__ float cstv_s[256];

    int t = threadIdx.x;
    int wid = t >> 6;
    int lane = t & 63;
    int n0 = blockIdx.x * 8;
    int n = n0 + wid;
    const float4* p4 = reinterpret_cast<const float4*>(p);

    if (FOLD && t < 256) cstv_s[t] = cstvg[t];

    float4 cv = make_float4(cvec[0], cvec[1], cvec[2], cvec[3]);
    if (t < 9) r_s[t] = rowptr[n0 + t];
    if (t >= 16 && t < 24) {
        int i = t - 16;
        float4 pd = p4[n0 + i];
        pdc_s[i] = make_float4(pd.x + cv.x, pd.y + cv.y, pd.z + cv.z, pd.w + cv.w);
    }

    float scl = FOLD ? scv[lane] : 1.0f;

    // self-loop attention = softmax(c), node-independent
    float smx = fmaxf(fmaxf(cv.x, cv.y), fmaxf(cv.z, cv.w));
    float se0 = __expf(cv.x - smx), se1 = __expf(cv.y - smx);
    float se2 = __expf(cv.z - smx), se3 = __expf(cv.w - smx);
    float sinv = 1.0f / (se0 + se1 + se2 + se3);
    float sl0 = se0 * sinv, sl1 = se1 * sinv, sl2 = se2 * sinv, sl3 = se3 * sinv;

    float hs = bf2f(hbf_in[(unsigned)(n * 64 + lane)]);
    float acc0 = sl0 * hs, acc1 = sl1 * hs, acc2 = sl2 * hs, acc3 = sl3 * hs;
    float zt0 = sl0, zt1 = sl1, zt2 = sl2, zt3 = sl3;

    __syncthreads();
    int base = r_s[0];
    int endb = r_s[8];
    int Eb = endb - base;
    int gs = r_s[wid];
    int ge = r_s[wid + 1];

    for (int eb = 0; eb < Eb; eb += 512) {
        int j = base + eb + t;
        if (j < endb) {
            // which of the 8 nodes owns slot j (r_s broadcast reads)
            int i = 0;
#pragma unroll
            for (int qq = 1; qq < 8; ++qq) i += (j >= r_s[qq]);
            int s = __builtin_nontemporal_load(&csr[j]);  // stream: don't cache
            float4 q = p4[(unsigned)s];        // 16B gather (keep in L2)
            float4 pdc = pdc_s[i];
            float l0 = pdc.x - q.x;
            float l1 = pdc.y - q.y;
            float l2 = pdc.z - q.z;
            float l3 = pdc.w - q.w;
            float mx = fmaxf(fmaxf(l0, l1), fmaxf(l2, l3));  // REQUIRED (R5 NaN)
            float e0 = __expf(l0 - mx);
            float e1 = __expf(l1 - mx);
            float e2 = __expf(l2 - mx);
            float e3 = __expf(l3 - mx);
            float inv = 1.0f / (e0 + e1 + e2 + e3);
            attn_f[t] = make_float4(e0 * inv, e1 * inv, e2 * inv, e3 * inv);
            src_f[t] = s;
        }
        __syncthreads();

        // aggregate this wave's node over the staged window
        int from = gs > base + eb ? gs : base + eb;
        int to = ge < base + eb + 512 ? ge : base + eb + 512;
        int li = from - base - eb;
        int cnt = to - from;
        int k = 0;
        for (; k + 4 <= cnt; k += 4) {
            float4 a0 = attn_f[li + k];
            int s0 = src_f[li + k];
            float4 a1 = attn_f[li + k + 1];
            int s1 = src_f[li + k + 1];
            float4 a2 = attn_f[li + k + 2];
            int s2 = src_f[li + k + 2];
            float4 a3 = attn_f[li + k + 3];
            int s3 = src_f[li + k + 3];
            float h0 = bf2f(hbf_in[(unsigned)(s0 * 64 + lane)]);
            float h1 = bf2f(hbf_in[(unsigned)(s1 * 64 + lane)]);
            float h2 = bf2f(hbf_in[(unsigned)(s2 * 64 + lane)]);
            float h3 = bf2f(hbf_in[(unsigned)(s3 * 64 + lane)]);
            acc0 += a0.x * h0 + a1.x * h1 + a2.x * h2 + a3.x * h3;
            acc1 += a0.y * h0 + a1.y * h1 + a2.y * h2 + a3.y * h3;
            acc2 += a0.z * h0 + a1.z * h1 + a2.z * h2 + a3.z * h3;
            acc3 += a0.w * h0 + a1.w * h1 + a2.w * h2 + a3.w * h3;
            zt0 += a0.x + a1.x + a2.x + a3.x;
            zt1 += a0.y + a1.y + a2.y + a3.y;
            zt2 += a0.z + a1.z + a2.z + a3.z;
            zt3 += a0.w + a1.w + a2.w + a3.w;
        }
        for (; k < cnt; ++k) {
            float4 a0 = attn_f[li + k];
            int s0 = src_f[li + k];
            float h0 = bf2f(hbf_in[(unsigned)(s0 * 64 + lane)]);
            acc0 += a0.x * h0;
            acc1 += a0.y * h0;
            acc2 += a0.z * h0;
            acc3 += a0.w * h0;
            zt0 += a0.x; zt1 += a0.y; zt2 += a0.z; zt3 += a0.w;
        }
        __syncthreads();   // protect flat arrays before next round (if any)
    }

    float invD = 1.0f / (float)(ge - gs + 1);
    float s = invD * scl;
    {
        ushort* zr = &zrow[wid][0];
        zr[lane]       = f2bf(acc0 * s);
        zr[64 + lane]  = f2bf(acc1 * s);
        zr[128 + lane] = f2bf(acc2 * s);
        zr[192 + lane] = f2bf(acc3 * s);
        if (lane == 0)
            zs_s[wid] = make_float4(zt0 * invD, zt1 * invD, zt2 * invD, zt3 * invD);
    }
    __syncthreads();

    // ---- phase B: waves 0..3, one o-tile each; waves 4..7 done ----
    if (wid >= 4) return;

    int col = lane & 15;
    int grp = lane >> 4;
    int r = (col < 8) ? col : 7;        // A rows 8..15 clamped (discarded)
    const ushort* zr = &zrow[r][0];
    const ushort* wbp = wb + ((size_t)(wid * 8) * 64 + lane) * 8;
    f32x4 acc = {0.0f, 0.0f, 0.0f, 0.0f};
#pragma unroll
    for (int kb = 0; kb < 8; ++kb) {
        bf16x8 a = *reinterpret_cast<const bf16x8*>(zr + kb * 32 + grp * 8);
        bf16x8 b = *reinterpret_cast<const bf16x8*>(wbp + (size_t)kb * 512);
        acc = __builtin_amdgcn_mfma_f32_16x16x32_bf16(a, b, acc, 0, 0, 0);
    }

    // D layout: row=(lane>>4)*4+i, col=lane&15. Valid rows 0..7 -> grp<2.
    float ls = 0.0f, lq = 0.0f;
    if (grp < 2) {
        int o = wid * 16 + col;
        float bval = bvec[o];
#pragma unroll
        for (int i = 0; i < 4; ++i) {
            int nn = n0 + grp * 4 + i;
            float v = acc[i] + bval;
            if (FOLD) {
                float4 zv = zs_s[grp * 4 + i];
                v += zv.x * cstv_s[o] + zv.y * cstv_s[64 + o] +
                     zv.z * cstv_s[128 + o] + zv.w * cstv_s[192 + o];
            }
            if (STATS) {
                v = fmaxf(v, 0.0f);
                __builtin_nontemporal_store(f2bf(v), &hbfout[(size_t)nn * 64 + o]);
                ls += v;
                lq += v * v;
            } else {
                __builtin_nontemporal_store(v, &hout[(size_t)nn * 64 + o]);
            }
        }
        if (STATS) {
            ls += __shfl_xor(ls, 16, 64);
            lq += __shfl_xor(lq, 16, 64);
            if (lane < 16) {
                float* so = stats_out + (blockIdx.x & (NSHARD - 1)) * 128;
                atomicAdd(&so[o], ls);
                atomicAdd(&so[64 + o], lq);
            }
        }
    }
}

extern "C" void kernel_launch(void* const* d_in, const int* in_sizes, int n_in,
                              void* d_out, int out_size, void* d_ws, size_t ws_size,
                              hipStream_t stream) {
    const float* x = (const float*)d_in[0];
    const void* ei = d_in[1];
    const float* W0 = (const float*)d_in[2];
    const float* U0 = (const float*)d_in[3];
    const float* c0 = (const float*)d_in[4];
    const float* b0 = (const float*)d_in[5];
    const float* g0 = (const float*)d_in[6];
    const float* bt0 = (const float*)d_in[7];
    const float* W1 = (const float*)d_in[8];
    const float* U1 = (const float*)d_in[9];
    const float* c1 = (const float*)d_in[10];
    const float* b1 = (const float*)d_in[11];
    const float* g1 = (const float*)d_in[12];
    const float* bt1 = (const float*)d_in[13];
    const float* W2 = (const float*)d_in[14];
    const float* U2 = (const float*)d_in[15];
    const float* c2 = (const float*)d_in[16];
    const float* b2 = (const float*)d_in[17];

    // workspace layout — all 16B-aligned
    ushort* xbf = (ushort*)d_ws;                      // NN*64 bf16
    ushort* hbfA = xbf + (size_t)NN * 64;             // NN*64 (double buffer A)
    ushort* hbfB = hbfA + (size_t)NN * 64;            // NN*64 (double buffer B)
    float* p = (float*)(hbfB + (size_t)NN * 64);      // NN*4
    float* cstv = p + (size_t)NN * 4;                 // 256
    float* scv = cstv + 256;                          // 64
    int* degi = (int*)(scv + 64);                     // NN (memset-zeroed)
    float* statsA = (float*)(degi + NN);              // 2*16*128 = 4096
    int* rowptr = (int*)(statsA + 4096);              // NN+4
    int* csr = rowptr + NN + 4;                       // NE
    ushort* wb = (ushort*)(csr + NE);                 // 3*16384 bf16
    float* stats0 = statsA;
    float* stats1 = statsA + 2048;

    // 9 stream ops (memset + 8 kernels)
    hipMemsetAsync(degi, 0, sizeof(int) * NN, stream);
    k_prep_hist<<<3946, 256, 0, stream>>>(x, W0, W1, W2, ei, xbf, wb,
                                          (int4*)statsA, degi);
    k_scan<<<1, 1024, 0, stream>>>(degi, rowptr);
    k_scatter_pk0<<<EBLK + PKBLK, 256, 0, stream>>>(ei, rowptr, degi, csr,
                                                    x, U0, p);

    // ---- layer 0: read xbf, write hbfA + stats0 shards ----
    k_fused<0, 1><<<FBLK, 512, 0, stream>>>(rowptr, csr, p, xbf, c0,
                                            nullptr, nullptr, wb, b0,
                                            nullptr, hbfA, stats0);
    // ---- layer 1: fold BN0; read hbfA, write hbfB + stats1 shards ----
    k_pk<<<PKBLK, 256, 0, stream>>>(hbfA, U1, stats0, g0, W1, bt0, p, cstv, scv);
    k_fused<1, 1><<<FBLK, 512, 0, stream>>>(rowptr, csr, p, hbfA, c1,
                                            scv, cstv, wb + 16384, b1,
                                            nullptr, hbfB, stats1);
    // ---- layer 2: fold BN1; read hbfB, write d_out (fp32) ----
    k_pk<<<PKBLK, 256, 0, stream>>>(hbfB, U2, stats1, g1, W2, bt1, p, cstv, scv);
    k_fused<1, 0><<<FBLK, 512, 0, stream>>>(rowptr, csr, p, hbfB, c2,
                                            scv, cstv, wb + 32768, b2,
                                            (float*)d_out, nullptr, nullptr);
}